// Round 1
// baseline (6591.307 us; speedup 1.0000x reference)
//
#include <hip/hip_runtime.h>

#define NN 100000
#define EE 1000000
#define DDIM 192
#define NLAYER 6
#define TRAIN 8192
#define SLOPE 0.01f
#define EPS_LN 1e-5f

__device__ __forceinline__ float lrelu(float v) { return v > 0.0f ? v : SLOPE * v; }

__device__ __forceinline__ float wave_sum(float s) {
    #pragma unroll
    for (int off = 32; off > 0; off >>= 1) s += __shfl_down(s, off);
    return __shfl(s, 0);
}

// ---------------------------------------------------------------------------
// Tiled fp32 GEMM: C[n x M] = act(A[n x K] @ W[K x M] + bias (+ res))
// BM=64, BN=64, BK=16, 256 threads, 4x4 register tile per thread.
// ---------------------------------------------------------------------------
template <bool BIAS, bool RELU, bool RES>
__global__ __launch_bounds__(256) void gemm_k(
    const float* __restrict__ A, const float* __restrict__ W,
    const float* __restrict__ bias, const float* __restrict__ res,
    float* __restrict__ C, int n, int K, int M, int ldc)
{
    __shared__ float As[16][64];
    __shared__ float Ws[16][64];
    const int tid = threadIdx.x;
    const int tx = tid & 15, ty = tid >> 4;
    const int row0 = blockIdx.x * 64;
    const int colblk = blockIdx.y * 64;
    const int arow = tid >> 2, ak = (tid & 3) * 4;   // A stage: row 0..63, k-chunk
    const int wk = tid >> 4, wc = (tid & 15) * 4;    // W stage: k 0..15, col-chunk
    float acc[4][4] = {};
    const int ktiles = K >> 4;
    for (int t = 0; t < ktiles; ++t) {
        const int k0 = t << 4;
        float4 a4 = make_float4(0.f, 0.f, 0.f, 0.f);
        const int gr = row0 + arow;
        if (gr < n) a4 = *(const float4*)(A + (size_t)gr * K + k0 + ak);
        As[ak + 0][arow] = a4.x; As[ak + 1][arow] = a4.y;
        As[ak + 2][arow] = a4.z; As[ak + 3][arow] = a4.w;
        *(float4*)&Ws[wk][wc] = *(const float4*)(W + (size_t)(k0 + wk) * M + colblk + wc);
        __syncthreads();
        #pragma unroll
        for (int k = 0; k < 16; ++k) {
            float af[4], wf[4];
            *(float4*)af = *(const float4*)&As[k][ty * 4];
            *(float4*)wf = *(const float4*)&Ws[k][tx * 4];
            #pragma unroll
            for (int i = 0; i < 4; ++i)
                #pragma unroll
                for (int j = 0; j < 4; ++j)
                    acc[i][j] = fmaf(af[i], wf[j], acc[i][j]);
        }
        __syncthreads();
    }
    const int colg = colblk + tx * 4;
    #pragma unroll
    for (int i = 0; i < 4; ++i) {
        const int gr = row0 + ty * 4 + i;
        if (gr >= n) return;  // no barriers after this point
        float v[4];
        #pragma unroll
        for (int j = 0; j < 4; ++j) {
            float x = acc[i][j];
            if (BIAS) x += bias[colg + j];
            v[j] = x;
        }
        if (RES) {
            float4 r = *(const float4*)(res + (size_t)gr * ldc + colg);
            v[0] += r.x; v[1] += r.y; v[2] += r.z; v[3] += r.w;
        }
        if (RELU) {
            v[0] = lrelu(v[0]); v[1] = lrelu(v[1]);
            v[2] = lrelu(v[2]); v[3] = lrelu(v[3]);
        }
        *(float4*)(C + (size_t)gr * ldc + colg) = make_float4(v[0], v[1], v[2], v[3]);
    }
}

// ---------------------------------------------------------------------------
// num_prop/comments_prop embed: x[:, 64:192]  (tiny K=6/7 GEMMs + lrelu)
// ---------------------------------------------------------------------------
__global__ __launch_bounds__(256) void embed_nc_k(
    const float* __restrict__ np_, const float* __restrict__ cp,
    const float* __restrict__ Wn, const float* __restrict__ bnum,
    const float* __restrict__ Wc, const float* __restrict__ bc,
    float* __restrict__ x)
{
    const int idx = blockIdx.x * 256 + threadIdx.x;
    if (idx >= NN * 128) return;
    const int node = idx >> 7;
    const int c = idx & 127;
    float acc;
    if (c < 64) {
        acc = bnum[c];
        #pragma unroll
        for (int k = 0; k < 6; ++k) acc = fmaf(np_[node * 6 + k], Wn[k * 64 + c], acc);
    } else {
        const int cc = c - 64;
        acc = bc[cc];
        #pragma unroll
        for (int k = 0; k < 7; ++k) acc = fmaf(cp[node * 7 + k], Wc[k * 64 + cc], acc);
    }
    x[(size_t)node * DDIM + 64 + c] = lrelu(acc);
}

// ---------------------------------------------------------------------------
// Row LayerNorm over D=192, in place. One wave per row.
// ---------------------------------------------------------------------------
__global__ __launch_bounds__(256) void ln_k(float* __restrict__ x,
    const float* __restrict__ g, const float* __restrict__ b)
{
    const int wave = threadIdx.x >> 6, lane = threadIdx.x & 63;
    const int row = blockIdx.x * 4 + wave;
    if (row >= NN) return;
    float* xr = x + (size_t)row * DDIM;
    const float v0 = xr[lane], v1 = xr[lane + 64], v2 = xr[lane + 128];
    const float mu = wave_sum(v0 + v1 + v2) * (1.0f / DDIM);
    const float d0 = v0 - mu, d1 = v1 - mu, d2 = v2 - mu;
    const float var = wave_sum(d0 * d0 + d1 * d1 + d2 * d2) * (1.0f / DDIM);
    const float rs = rsqrtf(var + EPS_LN);
    xr[lane]       = fmaf(d0 * rs, g[lane],       b[lane]);
    xr[lane + 64]  = fmaf(d1 * rs, g[lane + 64],  b[lane + 64]);
    xr[lane + 128] = fmaf(d2 * rs, g[lane + 128], b[lane + 128]);
}

// ---------------------------------------------------------------------------
// BatchNorm over N: stats (sum, sumsq per column), finalize, apply.
// ---------------------------------------------------------------------------
__global__ __launch_bounds__(192) void bn_stats_k(const float* __restrict__ x,
                                                  float* __restrict__ bns)
{
    const int j = threadIdx.x;  // 0..191
    const int r0 = blockIdx.x * 256;
    int r1 = r0 + 256; if (r1 > NN) r1 = NN;
    float s = 0.f, s2 = 0.f;
    for (int r = r0; r < r1; ++r) {
        const float v = x[(size_t)r * DDIM + j];
        s += v; s2 = fmaf(v, v, s2);
    }
    atomicAdd(&bns[j], s);
    atomicAdd(&bns[DDIM + j], s2);
}

__global__ __launch_bounds__(192) void bn_fin_k(float* __restrict__ bns,
    const float* __restrict__ g, const float* __restrict__ b)
{
    const int j = threadIdx.x;
    const float invN = 1.0f / (float)NN;
    const float mu = bns[j] * invN;
    const float var = bns[DDIM + j] * invN - mu * mu;
    const float sc = g[j] * rsqrtf(var + EPS_LN);
    bns[2 * DDIM + j] = sc;
    bns[3 * DDIM + j] = fmaf(-mu, sc, b[j]);
}

__global__ __launch_bounds__(256) void bn_apply_k(float* __restrict__ x,
                                                  const float* __restrict__ bns)
{
    const size_t idx = (size_t)blockIdx.x * 256 + threadIdx.x;
    if (idx >= (size_t)NN * DDIM / 4) return;
    float4 v = ((float4*)x)[idx];
    const int c = (int)((idx * 4) % DDIM);
    const float* sc = bns + 2 * DDIM;
    const float* sh = bns + 3 * DDIM;
    v.x = fmaf(v.x, sc[c], sh[c]);
    v.y = fmaf(v.y, sc[c + 1], sh[c + 1]);
    v.z = fmaf(v.z, sc[c + 2], sh[c + 2]);
    v.w = fmaf(v.w, sc[c + 3], sh[c + 3]);
    ((float4*)x)[idx] = v;
}

// ---------------------------------------------------------------------------
// Contrastive loss: row-normalize, sim GEMM with fused exp/row-sums, final.
// ---------------------------------------------------------------------------
__global__ __launch_bounds__(256) void fnorm_k(const float* __restrict__ x,
                                               float* __restrict__ fn)
{
    const int wave = threadIdx.x >> 6, lane = threadIdx.x & 63;
    const int row = blockIdx.x * 4 + wave;
    if (row >= TRAIN) return;
    const float* xr = x + (size_t)row * DDIM;
    const float v0 = xr[lane], v1 = xr[lane + 64], v2 = xr[lane + 128];
    const float q = wave_sum(v0 * v0 + v1 * v1 + v2 * v2);
    const float inv = 1.0f / sqrtf(q);
    float* fr = fn + (size_t)row * DDIM;
    fr[lane] = v0 * inv; fr[lane + 64] = v1 * inv; fr[lane + 128] = v2 * inv;
}

__global__ __launch_bounds__(256) void sim_k(const float* __restrict__ fn,
    const int* __restrict__ lab, float* __restrict__ row_ex, float* __restrict__ row_mt)
{
    __shared__ float As[16][64];
    __shared__ float Bs[16][64];
    __shared__ float red_a[64][17];
    __shared__ float red_b[64][17];
    const int tid = threadIdx.x;
    const int tx = tid & 15, ty = tid >> 4;
    const int i0 = blockIdx.x * 64, j0 = blockIdx.y * 64;
    const int lrow = tid >> 2, lk = (tid & 3) * 4;
    float acc[4][4] = {};
    for (int t = 0; t < 12; ++t) {
        const int k0 = t * 16;
        float4 a4 = *(const float4*)(fn + (size_t)(i0 + lrow) * DDIM + k0 + lk);
        As[lk + 0][lrow] = a4.x; As[lk + 1][lrow] = a4.y;
        As[lk + 2][lrow] = a4.z; As[lk + 3][lrow] = a4.w;
        float4 b4 = *(const float4*)(fn + (size_t)(j0 + lrow) * DDIM + k0 + lk);
        Bs[lk + 0][lrow] = b4.x; Bs[lk + 1][lrow] = b4.y;
        Bs[lk + 2][lrow] = b4.z; Bs[lk + 3][lrow] = b4.w;
        __syncthreads();
        #pragma unroll
        for (int k = 0; k < 16; ++k) {
            float af[4], wf[4];
            *(float4*)af = *(const float4*)&As[k][ty * 4];
            *(float4*)wf = *(const float4*)&Bs[k][tx * 4];
            #pragma unroll
            for (int i = 0; i < 4; ++i)
                #pragma unroll
                for (int j = 0; j < 4; ++j)
                    acc[i][j] = fmaf(af[i], wf[j], acc[i][j]);
        }
        __syncthreads();
    }
    int li[4], lj[4];
    #pragma unroll
    for (int i = 0; i < 4; ++i) li[i] = lab[i0 + ty * 4 + i];
    #pragma unroll
    for (int j = 0; j < 4; ++j) lj[j] = lab[j0 + tx * 4 + j];
    #pragma unroll
    for (int i = 0; i < 4; ++i) {
        float se = 0.f, sm = 0.f;
        #pragma unroll
        for (int j = 0; j < 4; ++j) {
            const float e = __expf(acc[i][j] * 2.0f);  // 1/TEMP = 2
            se += e;
            if (li[i] == lj[j]) sm += e;
        }
        red_a[ty * 4 + i][tx] = se;
        red_b[ty * 4 + i][tx] = sm;
    }
    __syncthreads();
    if (tid < 64) {
        float s = 0.f, m = 0.f;
        #pragma unroll
        for (int t2 = 0; t2 < 16; ++t2) { s += red_a[tid][t2]; m += red_b[tid][t2]; }
        atomicAdd(&row_ex[i0 + tid], s);
        atomicAdd(&row_mt[i0 + tid], m);
    }
}

__global__ __launch_bounds__(256) void closs_k(const float* __restrict__ ex,
    const float* __restrict__ mt, float* __restrict__ out)
{
    float s = 0.f;
    for (int i = threadIdx.x; i < TRAIN; i += 256) s += -logf(mt[i] / ex[i]);
    s = wave_sum(s);
    __shared__ float red[4];
    const int wave = threadIdx.x >> 6, lane = threadIdx.x & 63;
    if (lane == 0) red[wave] = s;
    __syncthreads();
    if (threadIdx.x == 0) out[0] = (red[0] + red[1] + red[2] + red[3]) / (float)TRAIN;
}

// ---------------------------------------------------------------------------
// RGCN: per-relation in-degree counts + scatter (agg/cnt folded into atomics)
// ---------------------------------------------------------------------------
__global__ __launch_bounds__(256) void cnt_k(const int* __restrict__ dst,
    const int* __restrict__ ety, float* __restrict__ cnt)
{
    const int e = blockIdx.x * 256 + threadIdx.x;
    if (e >= EE) return;
    atomicAdd(&cnt[(size_t)ety[e] * NN + dst[e]], 1.0f);
}

__global__ __launch_bounds__(256) void scatter_k(const float* __restrict__ h,
    const int* __restrict__ src, const int* __restrict__ dst, const int* __restrict__ ety,
    const float* __restrict__ cnt, float* __restrict__ out, int rel)
{
    const int wave = threadIdx.x >> 6, lane = threadIdx.x & 63;
    const int e = blockIdx.x * 4 + wave;
    if (e >= EE) return;
    if (ety[e] != rel) return;
    const int s = src[e], d = dst[e];
    const float inv = 1.0f / fmaxf(cnt[(size_t)rel * NN + d], 1.0f);
    const float* hr = h + (size_t)s * DDIM;
    float* orow = out + (size_t)d * DDIM;
    atomicAdd(&orow[lane],       hr[lane]       * inv);
    atomicAdd(&orow[lane + 64],  hr[lane + 64]  * inv);
    atomicAdd(&orow[lane + 128], hr[lane + 128] * inv);
}

// ---------------------------------------------------------------------------
// Final logits: M=2, one wave per row.
// ---------------------------------------------------------------------------
__global__ __launch_bounds__(256) void logits_k(const float* __restrict__ h,
    const float* __restrict__ Wm3, const float* __restrict__ bm3, float* __restrict__ out)
{
    const int wave = threadIdx.x >> 6, lane = threadIdx.x & 63;
    const int row = blockIdx.x * 4 + wave;
    if (row >= NN) return;
    const float* hr = h + (size_t)row * DDIM;
    float s0 = 0.f, s1 = 0.f;
    #pragma unroll
    for (int p = 0; p < 3; ++p) {
        const int k = lane + p * 64;
        const float v = hr[k];
        s0 = fmaf(v, Wm3[k * 2 + 0], s0);
        s1 = fmaf(v, Wm3[k * 2 + 1], s1);
    }
    #pragma unroll
    for (int off = 32; off > 0; off >>= 1) {
        s0 += __shfl_down(s0, off);
        s1 += __shfl_down(s1, off);
    }
    if (lane == 0) {
        out[(size_t)row * 2 + 0] = s0 + bm3[0];
        out[(size_t)row * 2 + 1] = s1 + bm3[1];
    }
}

// ---------------------------------------------------------------------------
extern "C" void kernel_launch(void* const* d_in, const int* in_sizes, int n_in,
                              void* d_out, int out_size, void* d_ws, size_t ws_size,
                              hipStream_t stream)
{
    const float* tweet   = (const float*)d_in[0];
    const float* np_     = (const float*)d_in[1];
    const float* cp      = (const float*)d_in[2];
    const float* Wt      = (const float*)d_in[3];
    const float* bt      = (const float*)d_in[4];
    const float* Wn      = (const float*)d_in[5];
    const float* bnum    = (const float*)d_in[6];
    const float* Wc      = (const float*)d_in[7];
    const float* bc      = (const float*)d_in[8];
    const float* Wv      = (const float*)d_in[9];
    const float* bv      = (const float*)d_in[10];
    const float* Wo      = (const float*)d_in[11];
    const float* bo      = (const float*)d_in[12];
    const float* ln1g    = (const float*)d_in[13];
    const float* ln1b    = (const float*)d_in[14];
    const float* bng     = (const float*)d_in[15];
    const float* bnb     = (const float*)d_in[16];
    const float* W1      = (const float*)d_in[17];
    const float* b1      = (const float*)d_in[18];
    const float* W2      = (const float*)d_in[19];
    const float* b2      = (const float*)d_in[20];
    const float* ln2g    = (const float*)d_in[21];
    const float* ln2b    = (const float*)d_in[22];
    const float* Wrel    = (const float*)d_in[23];
    const float* Wroot   = (const float*)d_in[24];
    const float* rgcnb   = (const float*)d_in[25];
    const float* Wm1     = (const float*)d_in[26];
    const float* bm1     = (const float*)d_in[27];
    const float* Wm2     = (const float*)d_in[28];
    const float* bm2     = (const float*)d_in[29];
    const float* Wm3     = (const float*)d_in[30];
    const float* bm3     = (const float*)d_in[31];
    const int*   eidx    = (const int*)d_in[32];
    const int*   esrc    = eidx;
    const int*   edst    = eidx + EE;
    const int*   ety     = (const int*)d_in[33];
    const int*   labels  = (const int*)d_in[34];
    // train_idx (d_in[35]) is a device scalar, fixed at 8192 by setup_inputs.
    float* out = (float*)d_out;

    float* ws = (float*)d_ws;
    const size_t ND = (size_t)NN * DDIM;
    float* B0    = ws;                       // x
    float* B1    = B0 + ND;
    float* B2    = B1 + ND;
    float* FN    = B2 + ND;                  // TRAIN x 192
    float* ROWEX = FN + (size_t)TRAIN * DDIM;
    float* ROWMT = ROWEX + TRAIN;
    float* CNT   = ROWMT + TRAIN;            // 2 x NN
    float* BNS   = CNT + 2 * (size_t)NN;     // 4 x 192 (sum, sumsq, scale, shift)

    const int gx = (NN + 63) / 64;           // 1563
    const dim3 blk(256);

    // ---- input embedding: x = [lrelu(tweet@Wt+bt) | lrelu(np@Wn+b) | lrelu(cp@Wc+b)]
    gemm_k<true, true, false><<<dim3(gx, 1), blk, 0, stream>>>(
        tweet, Wt, bt, nullptr, B0, NN, 768, 64, DDIM);
    embed_nc_k<<<(NN * 128 + 255) / 256, blk, 0, stream>>>(np_, cp, Wn, bnum, Wc, bc, B0);

    // ---- 6 transformer-ish layers
    for (int i = 0; i < NLAYER; ++i) {
        const size_t wo = (size_t)i * DDIM * DDIM;
        // v = x@Wv + bv
        gemm_k<true, false, false><<<dim3(gx, 3), blk, 0, stream>>>(
            B0, Wv + wo, bv + i * DDIM, nullptr, B1, NN, DDIM, DDIM, DDIM);
        // y = x + v@Wo + bo
        gemm_k<true, false, true><<<dim3(gx, 3), blk, 0, stream>>>(
            B1, Wo + wo, bo + i * DDIM, B0, B2, NN, DDIM, DDIM, DDIM);
        ln_k<<<(NN + 3) / 4, blk, 0, stream>>>(B2, ln1g + i * DDIM, ln1b + i * DDIM);
        hipMemsetAsync(BNS, 0, 2 * DDIM * sizeof(float), stream);
        bn_stats_k<<<(NN + 255) / 256, dim3(192), 0, stream>>>(B2, BNS);
        bn_fin_k<<<1, dim3(192), 0, stream>>>(BNS, bng + i * DDIM, bnb + i * DDIM);
        bn_apply_k<<<(int)((ND / 4 + 255) / 256), blk, 0, stream>>>(B2, BNS);
        // f1 = lrelu(x@W1 + b1)
        gemm_k<true, true, false><<<dim3(gx, 3), blk, 0, stream>>>(
            B2, W1 + wo, b1 + i * DDIM, nullptr, B1, NN, DDIM, DDIM, DDIM);
        // x = x + f1@W2 + b2
        gemm_k<true, false, true><<<dim3(gx, 3), blk, 0, stream>>>(
            B1, W2 + wo, b2 + i * DDIM, B2, B0, NN, DDIM, DDIM, DDIM);
        ln_k<<<(NN + 3) / 4, blk, 0, stream>>>(B0, ln2g + i * DDIM, ln2b + i * DDIM);
    }

    // ---- contrastive loss on first 8192 rows
    hipMemsetAsync(ROWEX, 0, 2 * TRAIN * sizeof(float), stream);
    fnorm_k<<<TRAIN / 4, blk, 0, stream>>>(B0, FN);
    sim_k<<<dim3(TRAIN / 64, TRAIN / 64), blk, 0, stream>>>(FN, labels, ROWEX, ROWMT);
    closs_k<<<1, blk, 0, stream>>>(ROWEX, ROWMT, out + 2 * (size_t)NN);

    // ---- per-relation in-degree counts (shared by both RGCN calls)
    hipMemsetAsync(CNT, 0, 2 * (size_t)NN * sizeof(float), stream);
    cnt_k<<<(EE + 255) / 256, blk, 0, stream>>>(edst, ety, CNT);

    // ---- RGCN pass 1: B0 -> B1
    gemm_k<true, false, false><<<dim3(gx, 3), blk, 0, stream>>>(
        B0, Wroot, rgcnb, nullptr, B1, NN, DDIM, DDIM, DDIM);
    for (int r = 0; r < 2; ++r) {
        gemm_k<false, false, false><<<dim3(gx, 3), blk, 0, stream>>>(
            B0, Wrel + (size_t)r * DDIM * DDIM, nullptr, nullptr, B2, NN, DDIM, DDIM, DDIM);
        scatter_k<<<(EE + 3) / 4, blk, 0, stream>>>(B2, esrc, edst, ety, CNT, B1, r);
    }
    // ---- RGCN pass 2: B1 -> B0
    gemm_k<true, false, false><<<dim3(gx, 3), blk, 0, stream>>>(
        B1, Wroot, rgcnb, nullptr, B0, NN, DDIM, DDIM, DDIM);
    for (int r = 0; r < 2; ++r) {
        gemm_k<false, false, false><<<dim3(gx, 3), blk, 0, stream>>>(
            B1, Wrel + (size_t)r * DDIM * DDIM, nullptr, nullptr, B2, NN, DDIM, DDIM, DDIM);
        scatter_k<<<(EE + 3) / 4, blk, 0, stream>>>(B2, esrc, edst, ety, CNT, B0, r);
    }

    // ---- MLP head
    gemm_k<true, true, false><<<dim3(gx, 3), blk, 0, stream>>>(
        B0, Wm1, bm1, nullptr, B1, NN, DDIM, DDIM, DDIM);
    gemm_k<true, true, false><<<dim3(gx, 3), blk, 0, stream>>>(
        B1, Wm2, bm2, nullptr, B2, NN, DDIM, DDIM, DDIM);
    logits_k<<<(NN + 3) / 4, blk, 0, stream>>>(B2, Wm3, bm3, out);
}

// Round 2
// 4030.726 us; speedup vs baseline: 1.6353x; 1.6353x over previous
//
#include <hip/hip_runtime.h>

#define NN 100000
#define EE 1000000
#define DDIM 192
#define NLAYER 6
#define TRAIN 8192
#define SLOPE 0.01f
#define EPS_LN 1e-5f

typedef float f32x4 __attribute__((ext_vector_type(4)));
typedef __bf16 bf16x8 __attribute__((ext_vector_type(8)));
typedef unsigned short ushort_t;
typedef unsigned int uint_t;

__device__ __forceinline__ float lrelu(float v) { return v > 0.0f ? v : SLOPE * v; }

__device__ __forceinline__ ushort_t f2bf(float f) {
    union { float f; uint_t u; } v; v.f = f;
    uint_t u = v.u;
    u += 0x7fffu + ((u >> 16) & 1u);   // RNE
    return (ushort_t)(u >> 16);
}

__device__ __forceinline__ float wave_sum(float s) {
    #pragma unroll
    for (int off = 32; off > 0; off >>= 1) s += __shfl_down(s, off);
    return __shfl(s, 0);
}

// ---------------------------------------------------------------------------
// One-shot weight prep: transpose + convert to bf16.  WT[m][k] = W[k][m].
// mats 0..28 are 192x192 (Wv*6, Wo*6, W1*6, W2*6, Wrel*2, Wroot, Wm1, Wm2);
// the tail blocks handle Wt (768x64 -> 64x768).
// ---------------------------------------------------------------------------
__global__ __launch_bounds__(256) void prep_w(
    const float* __restrict__ Wt, const float* __restrict__ Wv,
    const float* __restrict__ Wo, const float* __restrict__ W1,
    const float* __restrict__ W2, const float* __restrict__ Wrel,
    const float* __restrict__ Wroot, const float* __restrict__ Wm1,
    const float* __restrict__ Wm2, ushort_t* __restrict__ WTt,
    ushort_t* __restrict__ WTs)
{
    const int bid = blockIdx.x;
    if (bid < 29 * 144) {
        const int mat = bid / 144;
        const int o = (bid % 144) * 256 + threadIdx.x;   // < 36864
        const float* src;
        if      (mat <  6) src = Wv   + (size_t)mat * 36864;
        else if (mat < 12) src = Wo   + (size_t)(mat - 6)  * 36864;
        else if (mat < 18) src = W1   + (size_t)(mat - 12) * 36864;
        else if (mat < 24) src = W2   + (size_t)(mat - 18) * 36864;
        else if (mat < 26) src = Wrel + (size_t)(mat - 24) * 36864;
        else if (mat == 26) src = Wroot;
        else if (mat == 27) src = Wm1;
        else                src = Wm2;
        const int m = o / 192, k = o - m * 192;
        WTs[(size_t)mat * 36864 + o] = f2bf(src[(size_t)k * 192 + m]);
    } else {
        const int o = (bid - 29 * 144) * 256 + threadIdx.x;  // < 49152
        const int m = o / 768, k = o - m * 768;
        WTt[o] = f2bf(Wt[(size_t)k * 64 + m]);
    }
}

// ---------------------------------------------------------------------------
// MFMA GEMM: C[n x M] = epi(A[n x K] @ W[K x M]), M = NFRAG*16, block=128 rows
// x full M.  WT is bf16 [M][K].  Optional fused: bias, lrelu, residual,
// LayerNorm (per-row), BN-apply on A-load (BNIN) / on residual (BNRES).
// ---------------------------------------------------------------------------
template <int NFRAG, bool BIAS, bool RELU, bool RES, bool LNORM, bool BNIN, bool BNRES>
__global__ __launch_bounds__(256) void gemm_mfma(
    const float* __restrict__ A, const ushort_t* __restrict__ WT,
    const float* __restrict__ bias, const float* __restrict__ res,
    float* __restrict__ C, const float* __restrict__ bns,
    const float* __restrict__ lg, const float* __restrict__ lb,
    int n, int K, int ldc)
{
    __shared__ ushort_t As[128 * 32];
    __shared__ ushort_t Ws[NFRAG * 16 * 32];
    const int tid = threadIdx.x;
    const int lane = tid & 63, w = tid >> 6;
    const int quad = lane >> 4, l15 = lane & 15;
    const int row0 = blockIdx.x * 128;

    f32x4 acc[2][NFRAG];
    #pragma unroll
    for (int m = 0; m < 2; ++m)
        #pragma unroll
        for (int nf = 0; nf < NFRAG; ++nf)
            acc[m][nf] = (f32x4){0.f, 0.f, 0.f, 0.f};

    const int srow = tid >> 1, shalf = tid & 1;
    const bool arow_ok = (row0 + srow) < n;
    const float* aptr = A + (size_t)(row0 + srow) * K + shalf * 16;

    for (int k0 = 0; k0 < K; k0 += 32) {
        // ---- stage A tile (128 x 32 fp32 -> bf16), 16 elems/thread
        float f[16];
        if (arow_ok) {
            const float4* p = (const float4*)(aptr + k0);
            #pragma unroll
            for (int i = 0; i < 4; ++i) {
                const float4 t4 = p[i];
                f[i * 4 + 0] = t4.x; f[i * 4 + 1] = t4.y;
                f[i * 4 + 2] = t4.z; f[i * 4 + 3] = t4.w;
            }
        } else {
            #pragma unroll
            for (int i = 0; i < 16; ++i) f[i] = 0.f;
        }
        if (BNIN) {
            const float4* scp = (const float4*)(bns + 2 * DDIM + k0 + shalf * 16);
            const float4* shp = (const float4*)(bns + 3 * DDIM + k0 + shalf * 16);
            #pragma unroll
            for (int i = 0; i < 4; ++i) {
                const float4 sc = scp[i], sh = shp[i];
                f[i * 4 + 0] = fmaf(f[i * 4 + 0], sc.x, sh.x);
                f[i * 4 + 1] = fmaf(f[i * 4 + 1], sc.y, sh.y);
                f[i * 4 + 2] = fmaf(f[i * 4 + 2], sc.z, sh.z);
                f[i * 4 + 3] = fmaf(f[i * 4 + 3], sc.w, sh.w);
            }
        }
        uint_t u[8];
        #pragma unroll
        for (int i = 0; i < 8; ++i)
            u[i] = (uint_t)f2bf(f[2 * i]) | ((uint_t)f2bf(f[2 * i + 1]) << 16);
        uint4* dst = (uint4*)&As[srow * 32 + shalf * 16];
        dst[0] = make_uint4(u[0], u[1], u[2], u[3]);
        dst[1] = make_uint4(u[4], u[5], u[6], u[7]);

        // ---- stage W tile (NFRAG*16 cols x 32 k, already bf16 transposed)
        #pragma unroll
        for (int s = tid; s < NFRAG * 64; s += 256) {
            const int col = s >> 2, part = s & 3;
            *(uint4*)&Ws[col * 32 + part * 8] =
                *(const uint4*)(WT + (size_t)col * K + k0 + part * 8);
        }
        __syncthreads();

        const bf16x8 a0 = *(const bf16x8*)&As[(w * 32 + l15) * 32 + quad * 8];
        const bf16x8 a1 = *(const bf16x8*)&As[(w * 32 + 16 + l15) * 32 + quad * 8];
        #pragma unroll
        for (int nf = 0; nf < NFRAG; ++nf) {
            const bf16x8 b = *(const bf16x8*)&Ws[(nf * 16 + l15) * 32 + quad * 8];
            acc[0][nf] = __builtin_amdgcn_mfma_f32_16x16x32_bf16(a0, b, acc[0][nf], 0, 0, 0);
            acc[1][nf] = __builtin_amdgcn_mfma_f32_16x16x32_bf16(a1, b, acc[1][nf], 0, 0, 0);
        }
        __syncthreads();
    }

    // ---- epilogue
    int   col[NFRAG];
    float bia[NFRAG];
    #pragma unroll
    for (int nf = 0; nf < NFRAG; ++nf) {
        col[nf] = nf * 16 + l15;
        bia[nf] = BIAS ? bias[col[nf]] : 0.f;
    }
    float rsc[NFRAG], rsh[NFRAG];
    if (BNRES) {
        #pragma unroll
        for (int nf = 0; nf < NFRAG; ++nf) {
            rsc[nf] = bns[2 * DDIM + col[nf]];
            rsh[nf] = bns[3 * DDIM + col[nf]];
        }
    }
    #pragma unroll
    for (int m = 0; m < 2; ++m) {
        #pragma unroll
        for (int reg = 0; reg < 4; ++reg) {
            const int gr = row0 + w * 32 + m * 16 + quad * 4 + reg;
            const bool ok = gr < n;
            float v[NFRAG];
            #pragma unroll
            for (int nf = 0; nf < NFRAG; ++nf) {
                float x = acc[m][nf][reg] + bia[nf];
                if (RES) {
                    float r = ok ? res[(size_t)gr * ldc + col[nf]] : 0.f;
                    if (BNRES) r = fmaf(r, rsc[nf], rsh[nf]);
                    x += r;
                }
                v[nf] = x;
            }
            if (LNORM) {
                float s = 0.f, s2 = 0.f;
                #pragma unroll
                for (int nf = 0; nf < NFRAG; ++nf) { s += v[nf]; s2 = fmaf(v[nf], v[nf], s2); }
                #pragma unroll
                for (int off = 1; off < 16; off <<= 1) {
                    s  += __shfl_xor(s, off);
                    s2 += __shfl_xor(s2, off);
                }
                const float mu = s * (1.0f / DDIM);
                const float var = s2 * (1.0f / DDIM) - mu * mu;
                const float rs = rsqrtf(var + EPS_LN);
                #pragma unroll
                for (int nf = 0; nf < NFRAG; ++nf)
                    v[nf] = fmaf((v[nf] - mu) * rs, lg[col[nf]], lb[col[nf]]);
            }
            if (ok) {
                #pragma unroll
                for (int nf = 0; nf < NFRAG; ++nf) {
                    float x = v[nf];
                    if (RELU) x = lrelu(x);
                    C[(size_t)gr * ldc + col[nf]] = x;
                }
            }
        }
    }
}

// ---------------------------------------------------------------------------
// num_prop/comments_prop embed: x[:, 64:192]
// ---------------------------------------------------------------------------
__global__ __launch_bounds__(256) void embed_nc_k(
    const float* __restrict__ np_, const float* __restrict__ cp,
    const float* __restrict__ Wn, const float* __restrict__ bnum,
    const float* __restrict__ Wc, const float* __restrict__ bc,
    float* __restrict__ x)
{
    const int idx = blockIdx.x * 256 + threadIdx.x;
    if (idx >= NN * 128) return;
    const int node = idx >> 7;
    const int c = idx & 127;
    float acc;
    if (c < 64) {
        acc = bnum[c];
        #pragma unroll
        for (int k = 0; k < 6; ++k) acc = fmaf(np_[node * 6 + k], Wn[k * 64 + c], acc);
    } else {
        const int cc = c - 64;
        acc = bc[cc];
        #pragma unroll
        for (int k = 0; k < 7; ++k) acc = fmaf(cp[node * 7 + k], Wc[k * 64 + cc], acc);
    }
    x[(size_t)node * DDIM + 64 + c] = lrelu(acc);
}

// ---------------------------------------------------------------------------
// BatchNorm stats + finalize (apply is fused into the next GEMM)
// ---------------------------------------------------------------------------
__global__ __launch_bounds__(192) void bn_stats_k(const float* __restrict__ x,
                                                  float* __restrict__ bns)
{
    const int j = threadIdx.x;
    const int r0 = blockIdx.x * 256;
    int r1 = r0 + 256; if (r1 > NN) r1 = NN;
    float s = 0.f, s2 = 0.f;
    for (int r = r0; r < r1; ++r) {
        const float v = x[(size_t)r * DDIM + j];
        s += v; s2 = fmaf(v, v, s2);
    }
    atomicAdd(&bns[j], s);
    atomicAdd(&bns[DDIM + j], s2);
}

__global__ __launch_bounds__(192) void bn_fin_k(float* __restrict__ bns,
    const float* __restrict__ g, const float* __restrict__ b)
{
    const int j = threadIdx.x;
    const float invN = 1.0f / (float)NN;
    const float mu = bns[j] * invN;
    const float var = bns[DDIM + j] * invN - mu * mu;
    const float sc = g[j] * rsqrtf(var + EPS_LN);
    bns[2 * DDIM + j] = sc;
    bns[3 * DDIM + j] = fmaf(-mu, sc, b[j]);
}

// ---------------------------------------------------------------------------
// Contrastive: fnorm (fp32 in -> bf16 normalized rows), MFMA sim, closs
// ---------------------------------------------------------------------------
__global__ __launch_bounds__(256) void fnorm_k(const float* __restrict__ x,
                                               ushort_t* __restrict__ fnb)
{
    const int wave = threadIdx.x >> 6, lane = threadIdx.x & 63;
    const int row = blockIdx.x * 4 + wave;
    if (row >= TRAIN) return;
    const float* xr = x + (size_t)row * DDIM;
    const float v0 = xr[lane], v1 = xr[lane + 64], v2 = xr[lane + 128];
    const float q = wave_sum(v0 * v0 + v1 * v1 + v2 * v2);
    const float inv = 1.0f / sqrtf(q);
    ushort_t* fr = fnb + (size_t)row * DDIM;
    fr[lane]       = f2bf(v0 * inv);
    fr[lane + 64]  = f2bf(v1 * inv);
    fr[lane + 128] = f2bf(v2 * inv);
}

__global__ __launch_bounds__(256) void sim_mfma(const ushort_t* __restrict__ fnb,
    const int* __restrict__ lab, float* __restrict__ row_ex, float* __restrict__ row_mt)
{
    __shared__ ushort_t Ai[128 * 32];
    __shared__ ushort_t Bj[128 * 32];
    __shared__ int Li[128], Lj[128];
    const int tid = threadIdx.x, lane = tid & 63, w = tid >> 6;
    const int quad = lane >> 4, l15 = lane & 15;
    const int i0 = blockIdx.x * 128, j0 = blockIdx.y * 128;
    if (tid < 128) Li[tid] = lab[i0 + tid];
    else           Lj[tid - 128] = lab[j0 + tid - 128];
    const int iw = (w >> 1) * 64, jw = (w & 1) * 64;

    f32x4 acc[4][4];
    #pragma unroll
    for (int m = 0; m < 4; ++m)
        #pragma unroll
        for (int nf = 0; nf < 4; ++nf)
            acc[m][nf] = (f32x4){0.f, 0.f, 0.f, 0.f};

    for (int k0 = 0; k0 < DDIM; k0 += 32) {
        #pragma unroll
        for (int s = tid; s < 512; s += 256) {
            const int row = s >> 2, part = s & 3;
            *(uint4*)&Ai[row * 32 + part * 8] =
                *(const uint4*)(fnb + (size_t)(i0 + row) * DDIM + k0 + part * 8);
            *(uint4*)&Bj[row * 32 + part * 8] =
                *(const uint4*)(fnb + (size_t)(j0 + row) * DDIM + k0 + part * 8);
        }
        __syncthreads();
        bf16x8 a[4], b[4];
        #pragma unroll
        for (int m = 0; m < 4; ++m)
            a[m] = *(const bf16x8*)&Ai[(iw + m * 16 + l15) * 32 + quad * 8];
        #pragma unroll
        for (int nf = 0; nf < 4; ++nf)
            b[nf] = *(const bf16x8*)&Bj[(jw + nf * 16 + l15) * 32 + quad * 8];
        #pragma unroll
        for (int m = 0; m < 4; ++m)
            #pragma unroll
            for (int nf = 0; nf < 4; ++nf)
                acc[m][nf] = __builtin_amdgcn_mfma_f32_16x16x32_bf16(a[m], b[nf], acc[m][nf], 0, 0, 0);
        __syncthreads();
    }

    int lj[4];
    #pragma unroll
    for (int nf = 0; nf < 4; ++nf) lj[nf] = Lj[jw + nf * 16 + l15];
    #pragma unroll
    for (int m = 0; m < 4; ++m) {
        #pragma unroll
        for (int reg = 0; reg < 4; ++reg) {
            const int rl = iw + m * 16 + quad * 4 + reg;
            const int li = Li[rl];
            float se = 0.f, sm = 0.f;
            #pragma unroll
            for (int nf = 0; nf < 4; ++nf) {
                const float e = __expf(acc[m][nf][reg] * 2.0f);  // 1/TEMP = 2
                se += e;
                if (li == lj[nf]) sm += e;
            }
            #pragma unroll
            for (int off = 1; off < 16; off <<= 1) {
                se += __shfl_xor(se, off);
                sm += __shfl_xor(sm, off);
            }
            if (l15 == 0) {
                atomicAdd(&row_ex[i0 + rl], se);
                atomicAdd(&row_mt[i0 + rl], sm);
            }
        }
    }
}

__global__ __launch_bounds__(256) void closs_k(const float* __restrict__ ex,
    const float* __restrict__ mt, float* __restrict__ out)
{
    float s = 0.f;
    for (int i = threadIdx.x; i < TRAIN; i += 256) s += -logf(mt[i] / ex[i]);
    s = wave_sum(s);
    __shared__ float red[4];
    const int wave = threadIdx.x >> 6, lane = threadIdx.x & 63;
    if (lane == 0) red[wave] = s;
    __syncthreads();
    if (threadIdx.x == 0) out[0] = (red[0] + red[1] + red[2] + red[3]) / (float)TRAIN;
}

// ---------------------------------------------------------------------------
// RGCN count + scatter
// ---------------------------------------------------------------------------
__global__ __launch_bounds__(256) void cnt_k(const int* __restrict__ dst,
    const int* __restrict__ ety, float* __restrict__ cnt)
{
    const int e = blockIdx.x * 256 + threadIdx.x;
    if (e >= EE) return;
    atomicAdd(&cnt[(size_t)ety[e] * NN + dst[e]], 1.0f);
}

__global__ __launch_bounds__(256) void scatter_k(const float* __restrict__ h,
    const int* __restrict__ src, const int* __restrict__ dst, const int* __restrict__ ety,
    const float* __restrict__ cnt, float* __restrict__ out, int rel)
{
    const int wave = threadIdx.x >> 6, lane = threadIdx.x & 63;
    const int e = blockIdx.x * 4 + wave;
    if (e >= EE) return;
    if (ety[e] != rel) return;
    const int s = src[e], d = dst[e];
    const float inv = 1.0f / fmaxf(cnt[(size_t)rel * NN + d], 1.0f);
    const float* hr = h + (size_t)s * DDIM;
    float* orow = out + (size_t)d * DDIM;
    atomicAdd(&orow[lane],       hr[lane]       * inv);
    atomicAdd(&orow[lane + 64],  hr[lane + 64]  * inv);
    atomicAdd(&orow[lane + 128], hr[lane + 128] * inv);
}

__global__ __launch_bounds__(256) void logits_k(const float* __restrict__ h,
    const float* __restrict__ Wm3, const float* __restrict__ bm3, float* __restrict__ out)
{
    const int wave = threadIdx.x >> 6, lane = threadIdx.x & 63;
    const int row = blockIdx.x * 4 + wave;
    if (row >= NN) return;
    const float* hr = h + (size_t)row * DDIM;
    float s0 = 0.f, s1 = 0.f;
    #pragma unroll
    for (int p = 0; p < 3; ++p) {
        const int k = lane + p * 64;
        const float v = hr[k];
        s0 = fmaf(v, Wm3[k * 2 + 0], s0);
        s1 = fmaf(v, Wm3[k * 2 + 1], s1);
    }
    #pragma unroll
    for (int off = 32; off > 0; off >>= 1) {
        s0 += __shfl_down(s0, off);
        s1 += __shfl_down(s1, off);
    }
    if (lane == 0) {
        out[(size_t)row * 2 + 0] = s0 + bm3[0];
        out[(size_t)row * 2 + 1] = s1 + bm3[1];
    }
}

// ---------------------------------------------------------------------------
extern "C" void kernel_launch(void* const* d_in, const int* in_sizes, int n_in,
                              void* d_out, int out_size, void* d_ws, size_t ws_size,
                              hipStream_t stream)
{
    const float* tweet   = (const float*)d_in[0];
    const float* np_     = (const float*)d_in[1];
    const float* cp      = (const float*)d_in[2];
    const float* Wt      = (const float*)d_in[3];
    const float* bt      = (const float*)d_in[4];
    const float* Wn      = (const float*)d_in[5];
    const float* bnum    = (const float*)d_in[6];
    const float* Wc      = (const float*)d_in[7];
    const float* bc      = (const float*)d_in[8];
    const float* Wv      = (const float*)d_in[9];
    const float* bv      = (const float*)d_in[10];
    const float* Wo      = (const float*)d_in[11];
    const float* bo      = (const float*)d_in[12];
    const float* ln1g    = (const float*)d_in[13];
    const float* ln1b    = (const float*)d_in[14];
    const float* bng     = (const float*)d_in[15];
    const float* bnb     = (const float*)d_in[16];
    const float* W1      = (const float*)d_in[17];
    const float* b1      = (const float*)d_in[18];
    const float* W2      = (const float*)d_in[19];
    const float* b2      = (const float*)d_in[20];
    const float* ln2g    = (const float*)d_in[21];
    const float* ln2b    = (const float*)d_in[22];
    const float* Wrel    = (const float*)d_in[23];
    const float* Wroot   = (const float*)d_in[24];
    const float* rgcnb   = (const float*)d_in[25];
    const float* Wm1     = (const float*)d_in[26];
    const float* bm1     = (const float*)d_in[27];
    const float* Wm2     = (const float*)d_in[28];
    const float* bm2     = (const float*)d_in[29];
    const float* Wm3     = (const float*)d_in[30];
    const float* bm3     = (const float*)d_in[31];
    const int*   eidx    = (const int*)d_in[32];
    const int*   esrc    = eidx;
    const int*   edst    = eidx + EE;
    const int*   ety     = (const int*)d_in[33];
    const int*   labels  = (const int*)d_in[34];
    float* out = (float*)d_out;

    float* ws = (float*)d_ws;
    const size_t ND = (size_t)NN * DDIM;
    float* B0    = ws;
    float* B1    = B0 + ND;
    float* B2    = B1 + ND;
    float* ROWEX = B2 + ND;
    float* ROWMT = ROWEX + TRAIN;
    float* CNT   = ROWMT + TRAIN;
    float* BNS   = CNT + 2 * (size_t)NN;      // [sum | sumsq | scale | shift]
    ushort_t* FNb = (ushort_t*)(BNS + 4 * DDIM);
    ushort_t* WTt = FNb + (size_t)TRAIN * DDIM;   // tweet weight, 64x768
    ushort_t* WTs = WTt + 49152;                  // 29 x 36864
    ushort_t* WTv    = WTs;
    ushort_t* WTo    = WTs + (size_t)6  * 36864;
    ushort_t* WT1    = WTs + (size_t)12 * 36864;
    ushort_t* WT2    = WTs + (size_t)18 * 36864;
    ushort_t* WTrel  = WTs + (size_t)24 * 36864;
    ushort_t* WTroot = WTs + (size_t)26 * 36864;
    ushort_t* WTm1   = WTs + (size_t)27 * 36864;
    ushort_t* WTm2   = WTs + (size_t)28 * 36864;

    const int gx = (NN + 127) / 128;   // 782
    const dim3 blk(256);

    prep_w<<<29 * 144 + 192, blk, 0, stream>>>(Wt, Wv, Wo, W1, W2, Wrel, Wroot, Wm1, Wm2, WTt, WTs);

    // ---- input embedding
    gemm_mfma<4, true, true, false, false, false, false><<<gx, blk, 0, stream>>>(
        tweet, WTt, bt, nullptr, B0, nullptr, nullptr, nullptr, NN, 768, DDIM);
    embed_nc_k<<<(NN * 128 + 255) / 256, blk, 0, stream>>>(np_, cp, Wn, bnum, Wc, bc, B0);

    // ---- 6 layers
    for (int i = 0; i < NLAYER; ++i) {
        const size_t wo = (size_t)i * 36864;
        // v = x@Wv + bv
        gemm_mfma<12, true, false, false, false, false, false><<<gx, blk, 0, stream>>>(
            B0, WTv + wo, bv + i * DDIM, nullptr, B1, nullptr, nullptr, nullptr, NN, DDIM, DDIM);
        // x = ln1(x + v@Wo + bo)
        gemm_mfma<12, true, false, true, true, false, false><<<gx, blk, 0, stream>>>(
            B1, WTo + wo, bo + i * DDIM, B0, B2, nullptr, ln1g + i * DDIM, ln1b + i * DDIM, NN, DDIM, DDIM);
        hipMemsetAsync(BNS, 0, 2 * DDIM * sizeof(float), stream);
        bn_stats_k<<<(NN + 255) / 256, dim3(192), 0, stream>>>(B2, BNS);
        bn_fin_k<<<1, dim3(192), 0, stream>>>(BNS, bng + i * DDIM, bnb + i * DDIM);
        // f1 = lrelu(bn(x)@W1 + b1)   (BN applied on A-load)
        gemm_mfma<12, true, true, false, false, true, false><<<gx, blk, 0, stream>>>(
            B2, WT1 + wo, b1 + i * DDIM, nullptr, B1, BNS, nullptr, nullptr, NN, DDIM, DDIM);
        // x = ln2(bn(x) + f1@W2 + b2) (BN applied on residual read)
        gemm_mfma<12, true, false, true, true, false, true><<<gx, blk, 0, stream>>>(
            B1, WT2 + wo, b2 + i * DDIM, B2, B0, BNS, ln2g + i * DDIM, ln2b + i * DDIM, NN, DDIM, DDIM);
    }

    // ---- contrastive loss
    hipMemsetAsync(ROWEX, 0, 2 * TRAIN * sizeof(float), stream);
    fnorm_k<<<TRAIN / 4, blk, 0, stream>>>(B0, FNb);
    sim_mfma<<<dim3(TRAIN / 128, TRAIN / 128), blk, 0, stream>>>(FNb, labels, ROWEX, ROWMT);
    closs_k<<<1, blk, 0, stream>>>(ROWEX, ROWMT, out + 2 * (size_t)NN);

    // ---- RGCN counts
    hipMemsetAsync(CNT, 0, 2 * (size_t)NN * sizeof(float), stream);
    cnt_k<<<(EE + 255) / 256, blk, 0, stream>>>(edst, ety, CNT);

    // ---- RGCN pass 1: B0 -> B1
    gemm_mfma<12, true, false, false, false, false, false><<<gx, blk, 0, stream>>>(
        B0, WTroot, rgcnb, nullptr, B1, nullptr, nullptr, nullptr, NN, DDIM, DDIM);
    for (int r = 0; r < 2; ++r) {
        gemm_mfma<12, false, false, false, false, false, false><<<gx, blk, 0, stream>>>(
            B0, WTrel + (size_t)r * 36864, nullptr, nullptr, B2, nullptr, nullptr, nullptr, NN, DDIM, DDIM);
        scatter_k<<<(EE + 3) / 4, blk, 0, stream>>>(B2, esrc, edst, ety, CNT, B1, r);
    }
    // ---- RGCN pass 2: B1 -> B0
    gemm_mfma<12, true, false, false, false, false, false><<<gx, blk, 0, stream>>>(
        B1, WTroot, rgcnb, nullptr, B0, nullptr, nullptr, nullptr, NN, DDIM, DDIM);
    for (int r = 0; r < 2; ++r) {
        gemm_mfma<12, false, false, false, false, false, false><<<gx, blk, 0, stream>>>(
            B1, WTrel + (size_t)r * 36864, nullptr, nullptr, B2, nullptr, nullptr, nullptr, NN, DDIM, DDIM);
        scatter_k<<<(EE + 3) / 4, blk, 0, stream>>>(B2, esrc, edst, ety, CNT, B0, r);
    }

    // ---- MLP head
    gemm_mfma<12, true, true, false, false, false, false><<<gx, blk, 0, stream>>>(
        B0, WTm1, bm1, nullptr, B1, nullptr, nullptr, nullptr, NN, DDIM, DDIM);
    gemm_mfma<12, true, true, false, false, false, false><<<gx, blk, 0, stream>>>(
        B1, WTm2, bm2, nullptr, B2, nullptr, nullptr, nullptr, NN, DDIM, DDIM);
    logits_k<<<(NN + 3) / 4, blk, 0, stream>>>(B2, Wm3, bm3, out);
}

// Round 3
// 3407.764 us; speedup vs baseline: 1.9342x; 1.1828x over previous
//
#include <hip/hip_runtime.h>

#define NN 100000
#define EE 1000000
#define DDIM 192
#define NLAYER 6
#define TRAIN 8192
#define SLOPE 0.01f
#define EPS_LN 1e-5f

typedef float f32x4 __attribute__((ext_vector_type(4)));
typedef __bf16 bf16x8 __attribute__((ext_vector_type(8)));
typedef unsigned short ushort_t;
typedef unsigned int uint_t;

__device__ __forceinline__ float lrelu(float v) { return v > 0.0f ? v : SLOPE * v; }

__device__ __forceinline__ ushort_t f2bf(float f) {
    union { float f; uint_t u; } v; v.f = f;
    uint_t u = v.u;
    u += 0x7fffu + ((u >> 16) & 1u);   // RNE
    return (ushort_t)(u >> 16);
}

__device__ __forceinline__ float wave_sum(float s) {
    #pragma unroll
    for (int off = 32; off > 0; off >>= 1) s += __shfl_down(s, off);
    return __shfl(s, 0);
}

// ---------------------------------------------------------------------------
// One-shot weight prep: transpose + convert to bf16.  WT[m][k] = W[k][m].
// mats 0..23,26..28 -> WTs (192x192 each); mats 24,25 (Wrel) -> WTc as a
// concatenated K=384 matrix WTc[m][r*192+k]; tail blocks -> Wt (768x64).
// ---------------------------------------------------------------------------
__global__ __launch_bounds__(256) void prep_w(
    const float* __restrict__ Wt, const float* __restrict__ Wv,
    const float* __restrict__ Wo, const float* __restrict__ W1,
    const float* __restrict__ W2, const float* __restrict__ Wrel,
    const float* __restrict__ Wroot, const float* __restrict__ Wm1,
    const float* __restrict__ Wm2, ushort_t* __restrict__ WTt,
    ushort_t* __restrict__ WTs, ushort_t* __restrict__ WTc)
{
    const int bid = blockIdx.x;
    if (bid < 29 * 144) {
        const int mat = bid / 144;
        const int o = (bid % 144) * 256 + threadIdx.x;   // < 36864
        const float* src;
        if      (mat <  6) src = Wv   + (size_t)mat * 36864;
        else if (mat < 12) src = Wo   + (size_t)(mat - 6)  * 36864;
        else if (mat < 18) src = W1   + (size_t)(mat - 12) * 36864;
        else if (mat < 24) src = W2   + (size_t)(mat - 18) * 36864;
        else if (mat < 26) src = Wrel + (size_t)(mat - 24) * 36864;
        else if (mat == 26) src = Wroot;
        else if (mat == 27) src = Wm1;
        else                src = Wm2;
        const int m = o / 192, k = o - m * 192;
        const ushort_t b = f2bf(src[(size_t)k * 192 + m]);
        if (mat == 24 || mat == 25)
            WTc[(size_t)m * 384 + (mat - 24) * 192 + k] = b;
        else
            WTs[(size_t)mat * 36864 + o] = b;
    } else {
        const int o = (bid - 29 * 144) * 256 + threadIdx.x;  // < 49152
        const int m = o / 768, k = o - m * 768;
        WTt[o] = f2bf(Wt[(size_t)k * 64 + m]);
    }
}

// ---------------------------------------------------------------------------
// MFMA GEMM: C[n x M] = epi(A[n x K] @ W[K x M]), M = NFRAG*16, block=128 rows
// x full M.  WT is bf16 [M][K].  Optional fused: bias, lrelu, residual,
// LayerNorm (per-row), BN-apply on A-load (BNIN) / on residual (BNRES).
// ---------------------------------------------------------------------------
template <int NFRAG, bool BIAS, bool RELU, bool RES, bool LNORM, bool BNIN, bool BNRES>
__global__ __launch_bounds__(256) void gemm_mfma(
    const float* __restrict__ A, const ushort_t* __restrict__ WT,
    const float* __restrict__ bias, const float* __restrict__ res,
    float* __restrict__ C, const float* __restrict__ bns,
    const float* __restrict__ lg, const float* __restrict__ lb,
    int n, int K, int ldc)
{
    __shared__ ushort_t As[128 * 32];
    __shared__ ushort_t Ws[NFRAG * 16 * 32];
    const int tid = threadIdx.x;
    const int lane = tid & 63, w = tid >> 6;
    const int quad = lane >> 4, l15 = lane & 15;
    const int row0 = blockIdx.x * 128;

    f32x4 acc[2][NFRAG];
    #pragma unroll
    for (int m = 0; m < 2; ++m)
        #pragma unroll
        for (int nf = 0; nf < NFRAG; ++nf)
            acc[m][nf] = (f32x4){0.f, 0.f, 0.f, 0.f};

    const int srow = tid >> 1, shalf = tid & 1;
    const bool arow_ok = (row0 + srow) < n;
    const float* aptr = A + (size_t)(row0 + srow) * K + shalf * 16;

    for (int k0 = 0; k0 < K; k0 += 32) {
        // ---- stage A tile (128 x 32 fp32 -> bf16), 16 elems/thread
        float f[16];
        if (arow_ok) {
            const float4* p = (const float4*)(aptr + k0);
            #pragma unroll
            for (int i = 0; i < 4; ++i) {
                const float4 t4 = p[i];
                f[i * 4 + 0] = t4.x; f[i * 4 + 1] = t4.y;
                f[i * 4 + 2] = t4.z; f[i * 4 + 3] = t4.w;
            }
        } else {
            #pragma unroll
            for (int i = 0; i < 16; ++i) f[i] = 0.f;
        }
        if (BNIN) {
            const float4* scp = (const float4*)(bns + 2 * DDIM + k0 + shalf * 16);
            const float4* shp = (const float4*)(bns + 3 * DDIM + k0 + shalf * 16);
            #pragma unroll
            for (int i = 0; i < 4; ++i) {
                const float4 sc = scp[i], sh = shp[i];
                f[i * 4 + 0] = fmaf(f[i * 4 + 0], sc.x, sh.x);
                f[i * 4 + 1] = fmaf(f[i * 4 + 1], sc.y, sh.y);
                f[i * 4 + 2] = fmaf(f[i * 4 + 2], sc.z, sh.z);
                f[i * 4 + 3] = fmaf(f[i * 4 + 3], sc.w, sh.w);
            }
        }
        uint_t u[8];
        #pragma unroll
        for (int i = 0; i < 8; ++i)
            u[i] = (uint_t)f2bf(f[2 * i]) | ((uint_t)f2bf(f[2 * i + 1]) << 16);
        uint4* dst = (uint4*)&As[srow * 32 + shalf * 16];
        dst[0] = make_uint4(u[0], u[1], u[2], u[3]);
        dst[1] = make_uint4(u[4], u[5], u[6], u[7]);

        // ---- stage W tile (NFRAG*16 cols x 32 k, already bf16 transposed)
        #pragma unroll
        for (int s = tid; s < NFRAG * 64; s += 256) {
            const int col = s >> 2, part = s & 3;
            *(uint4*)&Ws[col * 32 + part * 8] =
                *(const uint4*)(WT + (size_t)col * K + k0 + part * 8);
        }
        __syncthreads();

        const bf16x8 a0 = *(const bf16x8*)&As[(w * 32 + l15) * 32 + quad * 8];
        const bf16x8 a1 = *(const bf16x8*)&As[(w * 32 + 16 + l15) * 32 + quad * 8];
        #pragma unroll
        for (int nf = 0; nf < NFRAG; ++nf) {
            const bf16x8 b = *(const bf16x8*)&Ws[(nf * 16 + l15) * 32 + quad * 8];
            acc[0][nf] = __builtin_amdgcn_mfma_f32_16x16x32_bf16(a0, b, acc[0][nf], 0, 0, 0);
            acc[1][nf] = __builtin_amdgcn_mfma_f32_16x16x32_bf16(a1, b, acc[1][nf], 0, 0, 0);
        }
        __syncthreads();
    }

    // ---- epilogue
    int   col[NFRAG];
    float bia[NFRAG];
    #pragma unroll
    for (int nf = 0; nf < NFRAG; ++nf) {
        col[nf] = nf * 16 + l15;
        bia[nf] = BIAS ? bias[col[nf]] : 0.f;
    }
    float rsc[NFRAG], rsh[NFRAG];
    if (BNRES) {
        #pragma unroll
        for (int nf = 0; nf < NFRAG; ++nf) {
            rsc[nf] = bns[2 * DDIM + col[nf]];
            rsh[nf] = bns[3 * DDIM + col[nf]];
        }
    }
    #pragma unroll
    for (int m = 0; m < 2; ++m) {
        #pragma unroll
        for (int reg = 0; reg < 4; ++reg) {
            const int gr = row0 + w * 32 + m * 16 + quad * 4 + reg;
            const bool ok = gr < n;
            float v[NFRAG];
            #pragma unroll
            for (int nf = 0; nf < NFRAG; ++nf) {
                float x = acc[m][nf][reg] + bia[nf];
                if (RES) {
                    float r = ok ? res[(size_t)gr * ldc + col[nf]] : 0.f;
                    if (BNRES) r = fmaf(r, rsc[nf], rsh[nf]);
                    x += r;
                }
                v[nf] = x;
            }
            if (LNORM) {
                float s = 0.f, s2 = 0.f;
                #pragma unroll
                for (int nf = 0; nf < NFRAG; ++nf) { s += v[nf]; s2 = fmaf(v[nf], v[nf], s2); }
                #pragma unroll
                for (int off = 1; off < 16; off <<= 1) {
                    s  += __shfl_xor(s, off);
                    s2 += __shfl_xor(s2, off);
                }
                const float mu = s * (1.0f / DDIM);
                const float var = s2 * (1.0f / DDIM) - mu * mu;
                const float rs = rsqrtf(var + EPS_LN);
                #pragma unroll
                for (int nf = 0; nf < NFRAG; ++nf)
                    v[nf] = fmaf((v[nf] - mu) * rs, lg[col[nf]], lb[col[nf]]);
            }
            if (ok) {
                #pragma unroll
                for (int nf = 0; nf < NFRAG; ++nf) {
                    float x = v[nf];
                    if (RELU) x = lrelu(x);
                    C[(size_t)gr * ldc + col[nf]] = x;
                }
            }
        }
    }
}

// ---------------------------------------------------------------------------
// num_prop/comments_prop embed: x[:, 64:192]
// ---------------------------------------------------------------------------
__global__ __launch_bounds__(256) void embed_nc_k(
    const float* __restrict__ np_, const float* __restrict__ cp,
    const float* __restrict__ Wn, const float* __restrict__ bnum,
    const float* __restrict__ Wc, const float* __restrict__ bc,
    float* __restrict__ x)
{
    const int idx = blockIdx.x * 256 + threadIdx.x;
    if (idx >= NN * 128) return;
    const int node = idx >> 7;
    const int c = idx & 127;
    float acc;
    if (c < 64) {
        acc = bnum[c];
        #pragma unroll
        for (int k = 0; k < 6; ++k) acc = fmaf(np_[node * 6 + k], Wn[k * 64 + c], acc);
    } else {
        const int cc = c - 64;
        acc = bc[cc];
        #pragma unroll
        for (int k = 0; k < 7; ++k) acc = fmaf(cp[node * 7 + k], Wc[k * 64 + cc], acc);
    }
    x[(size_t)node * DDIM + 64 + c] = lrelu(acc);
}

// ---------------------------------------------------------------------------
// BatchNorm stats + finalize (apply is fused into the next GEMM)
// ---------------------------------------------------------------------------
__global__ __launch_bounds__(192) void bn_stats_k(const float* __restrict__ x,
                                                  float* __restrict__ bns)
{
    const int j = threadIdx.x;
    const int r0 = blockIdx.x * 256;
    int r1 = r0 + 256; if (r1 > NN) r1 = NN;
    float s = 0.f, s2 = 0.f;
    for (int r = r0; r < r1; ++r) {
        const float v = x[(size_t)r * DDIM + j];
        s += v; s2 = fmaf(v, v, s2);
    }
    atomicAdd(&bns[j], s);
    atomicAdd(&bns[DDIM + j], s2);
}

__global__ __launch_bounds__(192) void bn_fin_k(float* __restrict__ bns,
    const float* __restrict__ g, const float* __restrict__ b)
{
    const int j = threadIdx.x;
    const float invN = 1.0f / (float)NN;
    const float mu = bns[j] * invN;
    const float var = bns[DDIM + j] * invN - mu * mu;
    const float sc = g[j] * rsqrtf(var + EPS_LN);
    bns[2 * DDIM + j] = sc;
    bns[3 * DDIM + j] = fmaf(-mu, sc, b[j]);
}

// ---------------------------------------------------------------------------
// Contrastive: fnorm (fp32 in -> bf16 normalized rows), MFMA sim, closs
// ---------------------------------------------------------------------------
__global__ __launch_bounds__(256) void fnorm_k(const float* __restrict__ x,
                                               ushort_t* __restrict__ fnb)
{
    const int wave = threadIdx.x >> 6, lane = threadIdx.x & 63;
    const int row = blockIdx.x * 4 + wave;
    if (row >= TRAIN) return;
    const float* xr = x + (size_t)row * DDIM;
    const float v0 = xr[lane], v1 = xr[lane + 64], v2 = xr[lane + 128];
    const float q = wave_sum(v0 * v0 + v1 * v1 + v2 * v2);
    const float inv = 1.0f / sqrtf(q);
    ushort_t* fr = fnb + (size_t)row * DDIM;
    fr[lane]       = f2bf(v0 * inv);
    fr[lane + 64]  = f2bf(v1 * inv);
    fr[lane + 128] = f2bf(v2 * inv);
}

__global__ __launch_bounds__(256) void sim_mfma(const ushort_t* __restrict__ fnb,
    const int* __restrict__ lab, float* __restrict__ row_ex, float* __restrict__ row_mt)
{
    __shared__ ushort_t Ai[128 * 32];
    __shared__ ushort_t Bj[128 * 32];
    __shared__ int Li[128], Lj[128];
    const int tid = threadIdx.x, lane = tid & 63, w = tid >> 6;
    const int quad = lane >> 4, l15 = lane & 15;
    const int i0 = blockIdx.x * 128, j0 = blockIdx.y * 128;
    if (tid < 128) Li[tid] = lab[i0 + tid];
    else           Lj[tid - 128] = lab[j0 + tid - 128];
    const int iw = (w >> 1) * 64, jw = (w & 1) * 64;

    f32x4 acc[4][4];
    #pragma unroll
    for (int m = 0; m < 4; ++m)
        #pragma unroll
        for (int nf = 0; nf < 4; ++nf)
            acc[m][nf] = (f32x4){0.f, 0.f, 0.f, 0.f};

    for (int k0 = 0; k0 < DDIM; k0 += 32) {
        #pragma unroll
        for (int s = tid; s < 512; s += 256) {
            const int row = s >> 2, part = s & 3;
            *(uint4*)&Ai[row * 32 + part * 8] =
                *(const uint4*)(fnb + (size_t)(i0 + row) * DDIM + k0 + part * 8);
            *(uint4*)&Bj[row * 32 + part * 8] =
                *(const uint4*)(fnb + (size_t)(j0 + row) * DDIM + k0 + part * 8);
        }
        __syncthreads();
        bf16x8 a[4], b[4];
        #pragma unroll
        for (int m = 0; m < 4; ++m)
            a[m] = *(const bf16x8*)&Ai[(iw + m * 16 + l15) * 32 + quad * 8];
        #pragma unroll
        for (int nf = 0; nf < 4; ++nf)
            b[nf] = *(const bf16x8*)&Bj[(jw + nf * 16 + l15) * 32 + quad * 8];
        #pragma unroll
        for (int m = 0; m < 4; ++m)
            #pragma unroll
            for (int nf = 0; nf < 4; ++nf)
                acc[m][nf] = __builtin_amdgcn_mfma_f32_16x16x32_bf16(a[m], b[nf], acc[m][nf], 0, 0, 0);
        __syncthreads();
    }

    int lj[4];
    #pragma unroll
    for (int nf = 0; nf < 4; ++nf) lj[nf] = Lj[jw + nf * 16 + l15];
    #pragma unroll
    for (int m = 0; m < 4; ++m) {
        #pragma unroll
        for (int reg = 0; reg < 4; ++reg) {
            const int rl = iw + m * 16 + quad * 4 + reg;
            const int li = Li[rl];
            float se = 0.f, sm = 0.f;
            #pragma unroll
            for (int nf = 0; nf < 4; ++nf) {
                const float e = __expf(acc[m][nf][reg] * 2.0f);  // 1/TEMP = 2
                se += e;
                if (li == lj[nf]) sm += e;
            }
            #pragma unroll
            for (int off = 1; off < 16; off <<= 1) {
                se += __shfl_xor(se, off);
                sm += __shfl_xor(sm, off);
            }
            if (l15 == 0) {
                atomicAdd(&row_ex[i0 + rl], se);
                atomicAdd(&row_mt[i0 + rl], sm);
            }
        }
    }
}

__global__ __launch_bounds__(256) void closs_k(const float* __restrict__ ex,
    const float* __restrict__ mt, float* __restrict__ out)
{
    float s = 0.f;
    for (int i = threadIdx.x; i < TRAIN; i += 256) s += -logf(mt[i] / ex[i]);
    s = wave_sum(s);
    __shared__ float red[4];
    const int wave = threadIdx.x >> 6, lane = threadIdx.x & 63;
    if (lane == 0) red[wave] = s;
    __syncthreads();
    if (threadIdx.x == 0) out[0] = (red[0] + red[1] + red[2] + red[3]) / (float)TRAIN;
}

// ---------------------------------------------------------------------------
// CSR build: per-(rel,dst) counts -> exclusive scan -> fill (atomic cursor
// trick turns OFFS into end-offsets; gather recomputes beg = end - cnt).
// ---------------------------------------------------------------------------
__global__ __launch_bounds__(256) void cnt_i_k(const int* __restrict__ dst,
    const int* __restrict__ ety, int* __restrict__ cnti)
{
    const int e = blockIdx.x * 256 + threadIdx.x;
    if (e >= EE) return;
    atomicAdd(&cnti[(size_t)ety[e] * NN + dst[e]], 1);
}

#define SCAN_T 1024
__global__ __launch_bounds__(SCAN_T) void scan_k(const int* __restrict__ cnti,
                                                 int* __restrict__ offs)
{
    __shared__ int sh[SCAN_T];
    __shared__ int run_s;
    const int tid = threadIdx.x;
    if (tid == 0) run_s = 0;
    __syncthreads();
    const int TOT = 2 * NN;
    for (int base = 0; base < TOT; base += SCAN_T * 8) {
        int v[8];
        int loc = 0;
        const int i0 = base + tid * 8;
        #pragma unroll
        for (int j = 0; j < 8; ++j) {
            const int i = i0 + j;
            v[j] = (i < TOT) ? cnti[i] : 0;
            loc += v[j];
        }
        sh[tid] = loc;
        __syncthreads();
        #pragma unroll
        for (int off = 1; off < SCAN_T; off <<= 1) {
            const int t = (tid >= off) ? sh[tid - off] : 0;
            __syncthreads();
            sh[tid] += t;
            __syncthreads();
        }
        int pre = run_s + sh[tid] - loc;   // exclusive prefix of this thread's chunk
        #pragma unroll
        for (int j = 0; j < 8; ++j) {
            const int i = i0 + j;
            if (i < TOT) offs[i] = pre;
            pre += v[j];
        }
        __syncthreads();
        if (tid == 0) run_s += sh[SCAN_T - 1];
        __syncthreads();
    }
}

__global__ __launch_bounds__(256) void fill_k(const int* __restrict__ src,
    const int* __restrict__ dst, const int* __restrict__ ety,
    int* __restrict__ offs, int* __restrict__ elist)
{
    const int e = blockIdx.x * 256 + threadIdx.x;
    if (e >= EE) return;
    const int pos = atomicAdd(&offs[(size_t)ety[e] * NN + dst[e]], 1);
    elist[pos] = src[e];
}

// ---------------------------------------------------------------------------
// Gather: AGG[d][r*192+c] = mean over incoming type-r edges of x[src][c].
// One wave per dst node; 3 coalesced floats per lane per source row.
// ---------------------------------------------------------------------------
__global__ __launch_bounds__(256) void gather_k(const float* __restrict__ x,
    const int* __restrict__ elist, const int* __restrict__ offs,
    const int* __restrict__ cnti, float* __restrict__ agg)
{
    const int wave = threadIdx.x >> 6, lane = threadIdx.x & 63;
    const int d = blockIdx.x * 4 + wave;
    if (d >= NN) return;
    #pragma unroll
    for (int r = 0; r < 2; ++r) {
        const int seg = r * NN + d;
        const int end = offs[seg];
        const int c = cnti[seg];
        float a0 = 0.f, a1 = 0.f, a2 = 0.f;
        for (int e = end - c; e < end; ++e) {
            const int s = elist[e];
            const float* xr = x + (size_t)s * DDIM;
            a0 += xr[lane]; a1 += xr[lane + 64]; a2 += xr[lane + 128];
        }
        const float inv = 1.0f / (float)max(c, 1);
        float* ar = agg + (size_t)d * 384 + r * DDIM;
        ar[lane] = a0 * inv; ar[lane + 64] = a1 * inv; ar[lane + 128] = a2 * inv;
    }
}

__global__ __launch_bounds__(256) void logits_k(const float* __restrict__ h,
    const float* __restrict__ Wm3, const float* __restrict__ bm3, float* __restrict__ out)
{
    const int wave = threadIdx.x >> 6, lane = threadIdx.x & 63;
    const int row = blockIdx.x * 4 + wave;
    if (row >= NN) return;
    const float* hr = h + (size_t)row * DDIM;
    float s0 = 0.f, s1 = 0.f;
    #pragma unroll
    for (int p = 0; p < 3; ++p) {
        const int k = lane + p * 64;
        const float v = hr[k];
        s0 = fmaf(v, Wm3[k * 2 + 0], s0);
        s1 = fmaf(v, Wm3[k * 2 + 1], s1);
    }
    #pragma unroll
    for (int off = 32; off > 0; off >>= 1) {
        s0 += __shfl_down(s0, off);
        s1 += __shfl_down(s1, off);
    }
    if (lane == 0) {
        out[(size_t)row * 2 + 0] = s0 + bm3[0];
        out[(size_t)row * 2 + 1] = s1 + bm3[1];
    }
}

// ---------------------------------------------------------------------------
extern "C" void kernel_launch(void* const* d_in, const int* in_sizes, int n_in,
                              void* d_out, int out_size, void* d_ws, size_t ws_size,
                              hipStream_t stream)
{
    const float* tweet   = (const float*)d_in[0];
    const float* np_     = (const float*)d_in[1];
    const float* cp      = (const float*)d_in[2];
    const float* Wt      = (const float*)d_in[3];
    const float* bt      = (const float*)d_in[4];
    const float* Wn      = (const float*)d_in[5];
    const float* bnum    = (const float*)d_in[6];
    const float* Wc      = (const float*)d_in[7];
    const float* bc      = (const float*)d_in[8];
    const float* Wv      = (const float*)d_in[9];
    const float* bv      = (const float*)d_in[10];
    const float* Wo      = (const float*)d_in[11];
    const float* bo      = (const float*)d_in[12];
    const float* ln1g    = (const float*)d_in[13];
    const float* ln1b    = (const float*)d_in[14];
    const float* bng     = (const float*)d_in[15];
    const float* bnb     = (const float*)d_in[16];
    const float* W1      = (const float*)d_in[17];
    const float* b1      = (const float*)d_in[18];
    const float* W2      = (const float*)d_in[19];
    const float* b2      = (const float*)d_in[20];
    const float* ln2g    = (const float*)d_in[21];
    const float* ln2b    = (const float*)d_in[22];
    const float* Wrel    = (const float*)d_in[23];
    const float* Wroot   = (const float*)d_in[24];
    const float* rgcnb   = (const float*)d_in[25];
    const float* Wm1     = (const float*)d_in[26];
    const float* bm1     = (const float*)d_in[27];
    const float* Wm2     = (const float*)d_in[28];
    const float* bm2     = (const float*)d_in[29];
    const float* Wm3     = (const float*)d_in[30];
    const float* bm3     = (const float*)d_in[31];
    const int*   eidx    = (const int*)d_in[32];
    const int*   esrc    = eidx;
    const int*   edst    = eidx + EE;
    const int*   ety     = (const int*)d_in[33];
    const int*   labels  = (const int*)d_in[34];
    float* out = (float*)d_out;

    float* ws = (float*)d_ws;
    const size_t ND = (size_t)NN * DDIM;
    float* B0    = ws;
    float* B1    = B0 + ND;
    float* B2    = B1 + ND;       // also first half of AGG during RGCN
    float* B3    = B2 + ND;       // second half of AGG
    float* AGG   = B2;            // NN x 384 (contiguous across B2,B3)
    float* ROWEX = B3 + ND;
    float* ROWMT = ROWEX + TRAIN;
    float* BNS   = ROWMT + TRAIN;             // [sum | sumsq | scale | shift]
    int*   CNTI  = (int*)(BNS + 4 * DDIM);    // 2*NN
    int*   OFFS  = CNTI + 2 * NN;             // 2*NN (becomes end-offsets)
    int*   ELIST = OFFS + 2 * NN;             // EE
    ushort_t* FNb = (ushort_t*)(ELIST + EE);
    ushort_t* WTt = FNb + (size_t)TRAIN * DDIM;   // 64x768
    ushort_t* WTs = WTt + 49152;                  // 29 x 36864 (24/25 unused)
    ushort_t* WTc = WTs + (size_t)29 * 36864;     // 192 x 384 concat rel
    ushort_t* WTv    = WTs;
    ushort_t* WTo    = WTs + (size_t)6  * 36864;
    ushort_t* WT1    = WTs + (size_t)12 * 36864;
    ushort_t* WT2    = WTs + (size_t)18 * 36864;
    ushort_t* WTroot = WTs + (size_t)26 * 36864;
    ushort_t* WTm1   = WTs + (size_t)27 * 36864;
    ushort_t* WTm2   = WTs + (size_t)28 * 36864;

    const int gx = (NN + 127) / 128;   // 782
    const dim3 blk(256);

    prep_w<<<29 * 144 + 192, blk, 0, stream>>>(Wt, Wv, Wo, W1, W2, Wrel, Wroot, Wm1, Wm2, WTt, WTs, WTc);

    // ---- CSR build (edge structure only; reused by both RGCN layers)
    hipMemsetAsync(CNTI, 0, 2 * NN * sizeof(int), stream);
    cnt_i_k<<<(EE + 255) / 256, blk, 0, stream>>>(edst, ety, CNTI);
    scan_k<<<1, SCAN_T, 0, stream>>>(CNTI, OFFS);
    fill_k<<<(EE + 255) / 256, blk, 0, stream>>>(esrc, edst, ety, OFFS, ELIST);

    // ---- input embedding
    gemm_mfma<4, true, true, false, false, false, false><<<gx, blk, 0, stream>>>(
        tweet, WTt, bt, nullptr, B0, nullptr, nullptr, nullptr, NN, 768, DDIM);
    embed_nc_k<<<(NN * 128 + 255) / 256, blk, 0, stream>>>(np_, cp, Wn, bnum, Wc, bc, B0);

    // ---- 6 layers
    for (int i = 0; i < NLAYER; ++i) {
        const size_t wo = (size_t)i * 36864;
        gemm_mfma<12, true, false, false, false, false, false><<<gx, blk, 0, stream>>>(
            B0, WTv + wo, bv + i * DDIM, nullptr, B1, nullptr, nullptr, nullptr, NN, DDIM, DDIM);
        gemm_mfma<12, true, false, true, true, false, false><<<gx, blk, 0, stream>>>(
            B1, WTo + wo, bo + i * DDIM, B0, B2, nullptr, ln1g + i * DDIM, ln1b + i * DDIM, NN, DDIM, DDIM);
        hipMemsetAsync(BNS, 0, 2 * DDIM * sizeof(float), stream);
        bn_stats_k<<<(NN + 255) / 256, dim3(192), 0, stream>>>(B2, BNS);
        bn_fin_k<<<1, dim3(192), 0, stream>>>(BNS, bng + i * DDIM, bnb + i * DDIM);
        gemm_mfma<12, true, true, false, false, true, false><<<gx, blk, 0, stream>>>(
            B2, WT1 + wo, b1 + i * DDIM, nullptr, B1, BNS, nullptr, nullptr, NN, DDIM, DDIM);
        gemm_mfma<12, true, false, true, true, false, true><<<gx, blk, 0, stream>>>(
            B1, WT2 + wo, b2 + i * DDIM, B2, B0, BNS, ln2g + i * DDIM, ln2b + i * DDIM, NN, DDIM, DDIM);
    }

    // ---- contrastive loss (before RGCN so AGG can reuse B2/B3)
    hipMemsetAsync(ROWEX, 0, 2 * TRAIN * sizeof(float), stream);
    fnorm_k<<<TRAIN / 4, blk, 0, stream>>>(B0, FNb);
    sim_mfma<<<dim3(TRAIN / 128, TRAIN / 128), blk, 0, stream>>>(FNb, labels, ROWEX, ROWMT);
    closs_k<<<1, blk, 0, stream>>>(ROWEX, ROWMT, out + 2 * (size_t)NN);

    // ---- RGCN pass 1:  h = x@Wroot + b + [m0|m1]@[W0;W1]    (B0 -> B0)
    gather_k<<<(NN + 3) / 4, blk, 0, stream>>>(B0, ELIST, OFFS, CNTI, AGG);
    gemm_mfma<12, true, false, false, false, false, false><<<gx, blk, 0, stream>>>(
        B0, WTroot, rgcnb, nullptr, B1, nullptr, nullptr, nullptr, NN, DDIM, DDIM);
    gemm_mfma<12, false, false, true, false, false, false><<<gx, blk, 0, stream>>>(
        AGG, WTc, nullptr, B1, B0, nullptr, nullptr, nullptr, NN, 384, DDIM);

    // ---- RGCN pass 2 (B0 -> B0)
    gather_k<<<(NN + 3) / 4, blk, 0, stream>>>(B0, ELIST, OFFS, CNTI, AGG);
    gemm_mfma<12, true, false, false, false, false, false><<<gx, blk, 0, stream>>>(
        B0, WTroot, rgcnb, nullptr, B1, nullptr, nullptr, nullptr, NN, DDIM, DDIM);
    gemm_mfma<12, false, false, true, false, false, false><<<gx, blk, 0, stream>>>(
        AGG, WTc, nullptr, B1, B0, nullptr, nullptr, nullptr, NN, 384, DDIM);

    // ---- MLP head
    gemm_mfma<12, true, true, false, false, false, false><<<gx, blk, 0, stream>>>(
        B0, WTm1, bm1, nullptr, B1, nullptr, nullptr, nullptr, NN, DDIM, DDIM);
    gemm_mfma<12, true, true, false, false, false, false><<<gx, blk, 0, stream>>>(
        B1, WTm2, bm2, nullptr, B2, nullptr, nullptr, nullptr, NN, DDIM, DDIM);
    logits_k<<<(NN + 3) / 4, blk, 0, stream>>>(B2, Wm3, bm3, out);
}

// Round 4
// 3061.244 us; speedup vs baseline: 2.1531x; 1.1132x over previous
//
#include <hip/hip_runtime.h>

#define NN 100000
#define EE 1000000
#define DDIM 192
#define NLAYER 6
#define TRAIN 8192
#define SLOPE 0.01f
#define EPS_LN 1e-5f
#define TOTSEG (2 * NN)
#define SCAN_NB 98           /* ceil(200000 / 2048) */

typedef float f32x4 __attribute__((ext_vector_type(4)));
typedef __bf16 bf16x8 __attribute__((ext_vector_type(8)));
typedef unsigned short ushort_t;
typedef unsigned int uint_t;

__device__ __forceinline__ float lrelu(float v) { return v > 0.0f ? v : SLOPE * v; }

__device__ __forceinline__ ushort_t f2bf(float f) {
    union { float f; uint_t u; } v; v.f = f;
    uint_t u = v.u;
    u += 0x7fffu + ((u >> 16) & 1u);   // RNE
    return (ushort_t)(u >> 16);
}

__device__ __forceinline__ float wave_sum(float s) {
    #pragma unroll
    for (int off = 32; off > 0; off >>= 1) s += __shfl_down(s, off);
    return __shfl(s, 0);
}

// ---------------------------------------------------------------------------
// One-shot weight prep: transpose + convert to bf16.  WT[m][k] = W[k][m].
// ---------------------------------------------------------------------------
__global__ __launch_bounds__(256) void prep_w(
    const float* __restrict__ Wt, const float* __restrict__ Wv,
    const float* __restrict__ Wo, const float* __restrict__ W1,
    const float* __restrict__ W2, const float* __restrict__ Wrel,
    const float* __restrict__ Wroot, const float* __restrict__ Wm1,
    const float* __restrict__ Wm2, ushort_t* __restrict__ WTt,
    ushort_t* __restrict__ WTs, ushort_t* __restrict__ WTc)
{
    const int bid = blockIdx.x;
    if (bid < 29 * 144) {
        const int mat = bid / 144;
        const int o = (bid % 144) * 256 + threadIdx.x;   // < 36864
        const float* src;
        if      (mat <  6) src = Wv   + (size_t)mat * 36864;
        else if (mat < 12) src = Wo   + (size_t)(mat - 6)  * 36864;
        else if (mat < 18) src = W1   + (size_t)(mat - 12) * 36864;
        else if (mat < 24) src = W2   + (size_t)(mat - 18) * 36864;
        else if (mat < 26) src = Wrel + (size_t)(mat - 24) * 36864;
        else if (mat == 26) src = Wroot;
        else if (mat == 27) src = Wm1;
        else                src = Wm2;
        const int m = o / 192, k = o - m * 192;
        const ushort_t b = f2bf(src[(size_t)k * 192 + m]);
        if (mat == 24 || mat == 25)
            WTc[(size_t)m * 384 + (mat - 24) * 192 + k] = b;
        else
            WTs[(size_t)mat * 36864 + o] = b;
    } else {
        const int o = (bid - 29 * 144) * 256 + threadIdx.x;  // < 49152
        const int m = o / 768, k = o - m * 768;
        WTt[o] = f2bf(Wt[(size_t)k * 64 + m]);
    }
}

// ---------------------------------------------------------------------------
// MFMA GEMM with software-pipelined A loads.
// C[n x M] = epi(A[n x K] @ W[K x M]), M = NFRAG*16, block = 128 rows.
// Fused options: bias, lrelu, residual, per-row LayerNorm, BN-apply on
// A-load (BNIN) / residual (BNRES), BN-stats accumulation (BNSTAT).
// ---------------------------------------------------------------------------
template <int NFRAG, bool BIAS, bool RELU, bool RES, bool LNORM, bool BNIN,
          bool BNRES, bool BNSTAT>
__global__ __launch_bounds__(256) void gemm_mfma(
    const float* __restrict__ A, const ushort_t* __restrict__ WT,
    const float* __restrict__ bias, const float* __restrict__ res,
    float* __restrict__ C, const float* __restrict__ bns,
    float* __restrict__ bnacc,
    const float* __restrict__ lg, const float* __restrict__ lb,
    int n, int K, int ldc)
{
    __shared__ ushort_t As[128 * 32];
    __shared__ ushort_t Ws[NFRAG * 16 * 32];
    __shared__ float bsum[4][NFRAG * 16];
    __shared__ float bsum2[4][NFRAG * 16];
    const int tid = threadIdx.x;
    const int lane = tid & 63, w = tid >> 6;
    const int quad = lane >> 4, l15 = lane & 15;
    const int row0 = blockIdx.x * 128;

    f32x4 acc[2][NFRAG];
    #pragma unroll
    for (int m = 0; m < 2; ++m)
        #pragma unroll
        for (int nf = 0; nf < NFRAG; ++nf)
            acc[m][nf] = (f32x4){0.f, 0.f, 0.f, 0.f};

    const int srow = tid >> 1, shalf = tid & 1;
    const bool arow_ok = (row0 + srow) < n;
    const float* aptr = A + (size_t)(row0 + srow) * K + shalf * 16;
    const int ktiles = K >> 5;

    // prefetch tile 0 of A
    float f[16];
    if (arow_ok) {
        const float4* p = (const float4*)aptr;
        #pragma unroll
        for (int i = 0; i < 4; ++i) {
            const float4 t4 = p[i];
            f[i * 4 + 0] = t4.x; f[i * 4 + 1] = t4.y;
            f[i * 4 + 2] = t4.z; f[i * 4 + 3] = t4.w;
        }
    } else {
        #pragma unroll
        for (int i = 0; i < 16; ++i) f[i] = 0.f;
    }

    for (int t = 0; t < ktiles; ++t) {
        const int k0 = t << 5;
        // ---- convert tile t (in regs) -> LDS
        if (BNIN) {
            const float4* scp = (const float4*)(bns + 2 * DDIM + k0 + shalf * 16);
            const float4* shp = (const float4*)(bns + 3 * DDIM + k0 + shalf * 16);
            #pragma unroll
            for (int i = 0; i < 4; ++i) {
                const float4 sc = scp[i], sh = shp[i];
                f[i * 4 + 0] = fmaf(f[i * 4 + 0], sc.x, sh.x);
                f[i * 4 + 1] = fmaf(f[i * 4 + 1], sc.y, sh.y);
                f[i * 4 + 2] = fmaf(f[i * 4 + 2], sc.z, sh.z);
                f[i * 4 + 3] = fmaf(f[i * 4 + 3], sc.w, sh.w);
            }
        }
        uint_t u[8];
        #pragma unroll
        for (int i = 0; i < 8; ++i)
            u[i] = (uint_t)f2bf(f[2 * i]) | ((uint_t)f2bf(f[2 * i + 1]) << 16);
        uint4* dsta = (uint4*)&As[srow * 32 + shalf * 16];
        dsta[0] = make_uint4(u[0], u[1], u[2], u[3]);
        dsta[1] = make_uint4(u[4], u[5], u[6], u[7]);

        // ---- stage W tile t (L2-resident, short latency)
        #pragma unroll
        for (int s = tid; s < NFRAG * 64; s += 256) {
            const int col = s >> 2, part = s & 3;
            *(uint4*)&Ws[col * 32 + part * 8] =
                *(const uint4*)(WT + (size_t)col * K + k0 + part * 8);
        }
        __syncthreads();

        // ---- issue next A tile's global loads (overlap with MFMA phase)
        float fn_[16];
        const bool more = (t + 1 < ktiles);
        if (more) {
            if (arow_ok) {
                const float4* p = (const float4*)(aptr + k0 + 32);
                #pragma unroll
                for (int i = 0; i < 4; ++i) {
                    const float4 t4 = p[i];
                    fn_[i * 4 + 0] = t4.x; fn_[i * 4 + 1] = t4.y;
                    fn_[i * 4 + 2] = t4.z; fn_[i * 4 + 3] = t4.w;
                }
            } else {
                #pragma unroll
                for (int i = 0; i < 16; ++i) fn_[i] = 0.f;
            }
        }

        // ---- MFMA phase
        const bf16x8 a0 = *(const bf16x8*)&As[(w * 32 + l15) * 32 + quad * 8];
        const bf16x8 a1 = *(const bf16x8*)&As[(w * 32 + 16 + l15) * 32 + quad * 8];
        #pragma unroll
        for (int nf = 0; nf < NFRAG; ++nf) {
            const bf16x8 b = *(const bf16x8*)&Ws[(nf * 16 + l15) * 32 + quad * 8];
            acc[0][nf] = __builtin_amdgcn_mfma_f32_16x16x32_bf16(a0, b, acc[0][nf], 0, 0, 0);
            acc[1][nf] = __builtin_amdgcn_mfma_f32_16x16x32_bf16(a1, b, acc[1][nf], 0, 0, 0);
        }
        __syncthreads();
        if (more) {
            #pragma unroll
            for (int i = 0; i < 16; ++i) f[i] = fn_[i];
        }
    }

    // ---- epilogue
    int   col[NFRAG];
    float bia[NFRAG];
    #pragma unroll
    for (int nf = 0; nf < NFRAG; ++nf) {
        col[nf] = nf * 16 + l15;
        bia[nf] = BIAS ? bias[col[nf]] : 0.f;
    }
    float rsc[NFRAG], rsh[NFRAG];
    if (BNRES) {
        #pragma unroll
        for (int nf = 0; nf < NFRAG; ++nf) {
            rsc[nf] = bns[2 * DDIM + col[nf]];
            rsh[nf] = bns[3 * DDIM + col[nf]];
        }
    }
    float cs[NFRAG], cs2[NFRAG];
    if (BNSTAT) {
        #pragma unroll
        for (int nf = 0; nf < NFRAG; ++nf) { cs[nf] = 0.f; cs2[nf] = 0.f; }
    }
    #pragma unroll
    for (int m = 0; m < 2; ++m) {
        #pragma unroll
        for (int reg = 0; reg < 4; ++reg) {
            const int gr = row0 + w * 32 + m * 16 + quad * 4 + reg;
            const bool ok = gr < n;
            float v[NFRAG];
            #pragma unroll
            for (int nf = 0; nf < NFRAG; ++nf) {
                float x = acc[m][nf][reg] + bia[nf];
                if (RES) {
                    float r = ok ? res[(size_t)gr * ldc + col[nf]] : 0.f;
                    if (BNRES) r = fmaf(r, rsc[nf], rsh[nf]);
                    x += r;
                }
                v[nf] = x;
            }
            if (LNORM) {
                float s = 0.f, s2 = 0.f;
                #pragma unroll
                for (int nf = 0; nf < NFRAG; ++nf) { s += v[nf]; s2 = fmaf(v[nf], v[nf], s2); }
                #pragma unroll
                for (int off = 1; off < 16; off <<= 1) {
                    s  += __shfl_xor(s, off);
                    s2 += __shfl_xor(s2, off);
                }
                const float mu = s * (1.0f / DDIM);
                const float var = s2 * (1.0f / DDIM) - mu * mu;
                const float rs = rsqrtf(var + EPS_LN);
                #pragma unroll
                for (int nf = 0; nf < NFRAG; ++nf)
                    v[nf] = fmaf((v[nf] - mu) * rs, lg[col[nf]], lb[col[nf]]);
            }
            #pragma unroll
            for (int nf = 0; nf < NFRAG; ++nf) {
                float x = v[nf];
                if (RELU) x = lrelu(x);
                if (BNSTAT) {
                    const float xa = ok ? x : 0.f;
                    cs[nf] += xa;
                    cs2[nf] = fmaf(xa, xa, cs2[nf]);
                }
                if (ok) C[(size_t)gr * ldc + col[nf]] = x;
            }
        }
    }
    if (BNSTAT) {
        #pragma unroll
        for (int nf = 0; nf < NFRAG; ++nf) {
            cs[nf]  += __shfl_xor(cs[nf], 16);  cs[nf]  += __shfl_xor(cs[nf], 32);
            cs2[nf] += __shfl_xor(cs2[nf], 16); cs2[nf] += __shfl_xor(cs2[nf], 32);
        }
        if (quad == 0) {
            #pragma unroll
            for (int nf = 0; nf < NFRAG; ++nf) {
                bsum[w][nf * 16 + l15]  = cs[nf];
                bsum2[w][nf * 16 + l15] = cs2[nf];
            }
        }
        __syncthreads();
        if (tid < NFRAG * 16) {
            const float s  = bsum[0][tid] + bsum[1][tid] + bsum[2][tid] + bsum[3][tid];
            const float s2 = bsum2[0][tid] + bsum2[1][tid] + bsum2[2][tid] + bsum2[3][tid];
            atomicAdd(&bnacc[tid], s);
            atomicAdd(&bnacc[DDIM + tid], s2);
        }
    }
}

// ---------------------------------------------------------------------------
__global__ __launch_bounds__(256) void embed_nc_k(
    const float* __restrict__ np_, const float* __restrict__ cp,
    const float* __restrict__ Wn, const float* __restrict__ bnum,
    const float* __restrict__ Wc, const float* __restrict__ bc,
    float* __restrict__ x)
{
    const int idx = blockIdx.x * 256 + threadIdx.x;
    if (idx >= NN * 128) return;
    const int node = idx >> 7;
    const int c = idx & 127;
    float acc;
    if (c < 64) {
        acc = bnum[c];
        #pragma unroll
        for (int k = 0; k < 6; ++k) acc = fmaf(np_[node * 6 + k], Wn[k * 64 + c], acc);
    } else {
        const int cc = c - 64;
        acc = bc[cc];
        #pragma unroll
        for (int k = 0; k < 7; ++k) acc = fmaf(cp[node * 7 + k], Wc[k * 64 + cc], acc);
    }
    x[(size_t)node * DDIM + 64 + c] = lrelu(acc);
}

__global__ __launch_bounds__(192) void bn_fin_k(float* __restrict__ bns,
    const float* __restrict__ g, const float* __restrict__ b)
{
    const int j = threadIdx.x;
    const float invN = 1.0f / (float)NN;
    const float mu = bns[j] * invN;
    const float var = bns[DDIM + j] * invN - mu * mu;
    const float sc = g[j] * rsqrtf(var + EPS_LN);
    bns[2 * DDIM + j] = sc;
    bns[3 * DDIM + j] = fmaf(-mu, sc, b[j]);
}

// ---------------------------------------------------------------------------
// Contrastive: fnorm -> bf16 rows, MFMA sim, closs
// ---------------------------------------------------------------------------
__global__ __launch_bounds__(256) void fnorm_k(const float* __restrict__ x,
                                               ushort_t* __restrict__ fnb)
{
    const int wave = threadIdx.x >> 6, lane = threadIdx.x & 63;
    const int row = blockIdx.x * 4 + wave;
    if (row >= TRAIN) return;
    const float* xr = x + (size_t)row * DDIM;
    const float v0 = xr[lane], v1 = xr[lane + 64], v2 = xr[lane + 128];
    const float q = wave_sum(v0 * v0 + v1 * v1 + v2 * v2);
    const float inv = 1.0f / sqrtf(q);
    ushort_t* fr = fnb + (size_t)row * DDIM;
    fr[lane]       = f2bf(v0 * inv);
    fr[lane + 64]  = f2bf(v1 * inv);
    fr[lane + 128] = f2bf(v2 * inv);
}

__global__ __launch_bounds__(256) void sim_mfma(const ushort_t* __restrict__ fnb,
    const int* __restrict__ lab, float* __restrict__ row_ex, float* __restrict__ row_mt)
{
    __shared__ ushort_t Ai[128 * 32];
    __shared__ ushort_t Bj[128 * 32];
    __shared__ int Li[128], Lj[128];
    const int tid = threadIdx.x, lane = tid & 63, w = tid >> 6;
    const int quad = lane >> 4, l15 = lane & 15;
    const int i0 = blockIdx.x * 128, j0 = blockIdx.y * 128;
    if (tid < 128) Li[tid] = lab[i0 + tid];
    else           Lj[tid - 128] = lab[j0 + tid - 128];
    const int iw = (w >> 1) * 64, jw = (w & 1) * 64;

    f32x4 acc[4][4];
    #pragma unroll
    for (int m = 0; m < 4; ++m)
        #pragma unroll
        for (int nf = 0; nf < 4; ++nf)
            acc[m][nf] = (f32x4){0.f, 0.f, 0.f, 0.f};

    for (int k0 = 0; k0 < DDIM; k0 += 32) {
        #pragma unroll
        for (int s = tid; s < 512; s += 256) {
            const int row = s >> 2, part = s & 3;
            *(uint4*)&Ai[row * 32 + part * 8] =
                *(const uint4*)(fnb + (size_t)(i0 + row) * DDIM + k0 + part * 8);
            *(uint4*)&Bj[row * 32 + part * 8] =
                *(const uint4*)(fnb + (size_t)(j0 + row) * DDIM + k0 + part * 8);
        }
        __syncthreads();
        bf16x8 a[4], b[4];
        #pragma unroll
        for (int m = 0; m < 4; ++m)
            a[m] = *(const bf16x8*)&Ai[(iw + m * 16 + l15) * 32 + quad * 8];
        #pragma unroll
        for (int nf = 0; nf < 4; ++nf)
            b[nf] = *(const bf16x8*)&Bj[(jw + nf * 16 + l15) * 32 + quad * 8];
        #pragma unroll
        for (int m = 0; m < 4; ++m)
            #pragma unroll
            for (int nf = 0; nf < 4; ++nf)
                acc[m][nf] = __builtin_amdgcn_mfma_f32_16x16x32_bf16(a[m], b[nf], acc[m][nf], 0, 0, 0);
        __syncthreads();
    }

    int lj[4];
    #pragma unroll
    for (int nf = 0; nf < 4; ++nf) lj[nf] = Lj[jw + nf * 16 + l15];
    #pragma unroll
    for (int m = 0; m < 4; ++m) {
        #pragma unroll
        for (int reg = 0; reg < 4; ++reg) {
            const int rl = iw + m * 16 + quad * 4 + reg;
            const int li = Li[rl];
            float se = 0.f, sm = 0.f;
            #pragma unroll
            for (int nf = 0; nf < 4; ++nf) {
                const float e = __expf(acc[m][nf][reg] * 2.0f);  // 1/TEMP = 2
                se += e;
                if (li == lj[nf]) sm += e;
            }
            #pragma unroll
            for (int off = 1; off < 16; off <<= 1) {
                se += __shfl_xor(se, off);
                sm += __shfl_xor(sm, off);
            }
            if (l15 == 0) {
                atomicAdd(&row_ex[i0 + rl], se);
                atomicAdd(&row_mt[i0 + rl], sm);
            }
        }
    }
}

__global__ __launch_bounds__(256) void closs_k(const float* __restrict__ ex,
    const float* __restrict__ mt, float* __restrict__ out)
{
    float s = 0.f;
    for (int i = threadIdx.x; i < TRAIN; i += 256) s += -logf(mt[i] / ex[i]);
    s = wave_sum(s);
    __shared__ float red[4];
    const int wave = threadIdx.x >> 6, lane = threadIdx.x & 63;
    if (lane == 0) red[wave] = s;
    __syncthreads();
    if (threadIdx.x == 0) out[0] = (red[0] + red[1] + red[2] + red[3]) / (float)TRAIN;
}

// ---------------------------------------------------------------------------
// CSR build: counts -> 3-kernel parallel exclusive scan -> fill.
// ---------------------------------------------------------------------------
__global__ __launch_bounds__(256) void cnt_i_k(const int* __restrict__ dst,
    const int* __restrict__ ety, int* __restrict__ cnti)
{
    const int e = blockIdx.x * 256 + threadIdx.x;
    if (e >= EE) return;
    atomicAdd(&cnti[(size_t)ety[e] * NN + dst[e]], 1);
}

__global__ __launch_bounds__(256) void part_k(const int* __restrict__ cnti,
                                              int* __restrict__ part)
{
    __shared__ int sh[256];
    const int tid = threadIdx.x;
    const int i0 = blockIdx.x * 2048 + tid * 8;
    int s = 0;
    #pragma unroll
    for (int j = 0; j < 8; ++j) {
        const int i = i0 + j;
        s += (i < TOTSEG) ? cnti[i] : 0;
    }
    sh[tid] = s;
    __syncthreads();
    #pragma unroll
    for (int off = 128; off > 0; off >>= 1) {
        if (tid < off) sh[tid] += sh[tid + off];
        __syncthreads();
    }
    if (tid == 0) part[blockIdx.x] = sh[0];
}

__global__ __launch_bounds__(128) void scanp_k(int* __restrict__ part)
{
    __shared__ int sh[128];
    const int tid = threadIdx.x;
    const int v = (tid < SCAN_NB) ? part[tid] : 0;
    sh[tid] = v;
    __syncthreads();
    #pragma unroll
    for (int off = 1; off < 128; off <<= 1) {
        const int t = (tid >= off) ? sh[tid - off] : 0;
        __syncthreads();
        sh[tid] += t;
        __syncthreads();
    }
    if (tid < SCAN_NB) part[tid] = sh[tid] - v;   // exclusive
}

__global__ __launch_bounds__(256) void offs_k(const int* __restrict__ cnti,
    const int* __restrict__ part, int* __restrict__ offs)
{
    __shared__ int sh[256];
    const int tid = threadIdx.x;
    const int i0 = blockIdx.x * 2048 + tid * 8;
    int v[8];
    int loc = 0;
    #pragma unroll
    for (int j = 0; j < 8; ++j) {
        const int i = i0 + j;
        v[j] = (i < TOTSEG) ? cnti[i] : 0;
        loc += v[j];
    }
    sh[tid] = loc;
    __syncthreads();
    #pragma unroll
    for (int off = 1; off < 256; off <<= 1) {
        const int t = (tid >= off) ? sh[tid - off] : 0;
        __syncthreads();
        sh[tid] += t;
        __syncthreads();
    }
    int pre = part[blockIdx.x] + sh[tid] - loc;
    #pragma unroll
    for (int j = 0; j < 8; ++j) {
        const int i = i0 + j;
        if (i < TOTSEG) offs[i] = pre;
        pre += v[j];
    }
}

__global__ __launch_bounds__(256) void fill_k(const int* __restrict__ src,
    const int* __restrict__ dst, const int* __restrict__ ety,
    int* __restrict__ offs, int* __restrict__ elist)
{
    const int e = blockIdx.x * 256 + threadIdx.x;
    if (e >= EE) return;
    const int pos = atomicAdd(&offs[(size_t)ety[e] * NN + dst[e]], 1);
    elist[pos] = src[e];
}

// ---------------------------------------------------------------------------
// Gather: AGG[d][r*192+c] = mean over incoming type-r edges of x[src][c].
// ---------------------------------------------------------------------------
__global__ __launch_bounds__(256) void gather_k(const float* __restrict__ x,
    const int* __restrict__ elist, const int* __restrict__ offs,
    const int* __restrict__ cnti, float* __restrict__ agg)
{
    const int wave = threadIdx.x >> 6, lane = threadIdx.x & 63;
    const int d = blockIdx.x * 4 + wave;
    if (d >= NN) return;
    #pragma unroll
    for (int r = 0; r < 2; ++r) {
        const int seg = r * NN + d;
        const int end = offs[seg];
        const int c = cnti[seg];
        float a0 = 0.f, a1 = 0.f, a2 = 0.f;
        for (int e = end - c; e < end; ++e) {
            const int s = elist[e];
            const float* xr = x + (size_t)s * DDIM;
            a0 += xr[lane]; a1 += xr[lane + 64]; a2 += xr[lane + 128];
        }
        const float inv = 1.0f / (float)max(c, 1);
        float* ar = agg + (size_t)d * 384 + r * DDIM;
        ar[lane] = a0 * inv; ar[lane + 64] = a1 * inv; ar[lane + 128] = a2 * inv;
    }
}

__global__ __launch_bounds__(256) void logits_k(const float* __restrict__ h,
    const float* __restrict__ Wm3, const float* __restrict__ bm3, float* __restrict__ out)
{
    const int wave = threadIdx.x >> 6, lane = threadIdx.x & 63;
    const int row = blockIdx.x * 4 + wave;
    if (row >= NN) return;
    const float* hr = h + (size_t)row * DDIM;
    float s0 = 0.f, s1 = 0.f;
    #pragma unroll
    for (int p = 0; p < 3; ++p) {
        const int k = lane + p * 64;
        const float v = hr[k];
        s0 = fmaf(v, Wm3[k * 2 + 0], s0);
        s1 = fmaf(v, Wm3[k * 2 + 1], s1);
    }
    #pragma unroll
    for (int off = 32; off > 0; off >>= 1) {
        s0 += __shfl_down(s0, off);
        s1 += __shfl_down(s1, off);
    }
    if (lane == 0) {
        out[(size_t)row * 2 + 0] = s0 + bm3[0];
        out[(size_t)row * 2 + 1] = s1 + bm3[1];
    }
}

// ---------------------------------------------------------------------------
extern "C" void kernel_launch(void* const* d_in, const int* in_sizes, int n_in,
                              void* d_out, int out_size, void* d_ws, size_t ws_size,
                              hipStream_t stream)
{
    const float* tweet   = (const float*)d_in[0];
    const float* np_     = (const float*)d_in[1];
    const float* cp      = (const float*)d_in[2];
    const float* Wt      = (const float*)d_in[3];
    const float* bt      = (const float*)d_in[4];
    const float* Wn      = (const float*)d_in[5];
    const float* bnum    = (const float*)d_in[6];
    const float* Wc      = (const float*)d_in[7];
    const float* bc      = (const float*)d_in[8];
    const float* Wv      = (const float*)d_in[9];
    const float* bv      = (const float*)d_in[10];
    const float* Wo      = (const float*)d_in[11];
    const float* bo      = (const float*)d_in[12];
    const float* ln1g    = (const float*)d_in[13];
    const float* ln1b    = (const float*)d_in[14];
    const float* bng     = (const float*)d_in[15];
    const float* bnb     = (const float*)d_in[16];
    const float* W1      = (const float*)d_in[17];
    const float* b1      = (const float*)d_in[18];
    const float* W2      = (const float*)d_in[19];
    const float* b2      = (const float*)d_in[20];
    const float* ln2g    = (const float*)d_in[21];
    const float* ln2b    = (const float*)d_in[22];
    const float* Wrel    = (const float*)d_in[23];
    const float* Wroot   = (const float*)d_in[24];
    const float* rgcnb   = (const float*)d_in[25];
    const float* Wm1     = (const float*)d_in[26];
    const float* bm1     = (const float*)d_in[27];
    const float* Wm2     = (const float*)d_in[28];
    const float* bm2     = (const float*)d_in[29];
    const float* Wm3     = (const float*)d_in[30];
    const float* bm3     = (const float*)d_in[31];
    const int*   eidx    = (const int*)d_in[32];
    const int*   esrc    = eidx;
    const int*   edst    = eidx + EE;
    const int*   ety     = (const int*)d_in[33];
    const int*   labels  = (const int*)d_in[34];
    float* out = (float*)d_out;

    float* ws = (float*)d_ws;
    const size_t ND = (size_t)NN * DDIM;
    float* B0    = ws;
    float* B1    = B0 + ND;
    float* B2    = B1 + ND;       // also first half of AGG during RGCN
    float* B3    = B2 + ND;       // second half of AGG
    float* AGG   = B2;            // NN x 384 (contiguous across B2,B3)
    float* ROWEX = B3 + ND;
    float* ROWMT = ROWEX + TRAIN;
    float* BNS   = ROWMT + TRAIN;             // [sum | sumsq | scale | shift]
    int*   CNTI  = (int*)(BNS + 4 * DDIM);    // 2*NN
    int*   OFFS  = CNTI + 2 * NN;             // 2*NN (becomes end-offsets)
    int*   ELIST = OFFS + 2 * NN;             // EE
    int*   PART  = ELIST + EE;                // 128
    ushort_t* FNb = (ushort_t*)(PART + 128);
    ushort_t* WTt = FNb + (size_t)TRAIN * DDIM;   // 64x768
    ushort_t* WTs = WTt + 49152;                  // 29 x 36864 (24/25 unused)
    ushort_t* WTc = WTs + (size_t)29 * 36864;     // 192 x 384 concat rel
    ushort_t* WTv    = WTs;
    ushort_t* WTo    = WTs + (size_t)6  * 36864;
    ushort_t* WT1    = WTs + (size_t)12 * 36864;
    ushort_t* WT2    = WTs + (size_t)18 * 36864;
    ushort_t* WTroot = WTs + (size_t)26 * 36864;
    ushort_t* WTm1   = WTs + (size_t)27 * 36864;
    ushort_t* WTm2   = WTs + (size_t)28 * 36864;

    const int gx = (NN + 127) / 128;   // 782
    const dim3 blk(256);

    prep_w<<<29 * 144 + 192, blk, 0, stream>>>(Wt, Wv, Wo, W1, W2, Wrel, Wroot, Wm1, Wm2, WTt, WTs, WTc);

    // ---- CSR build (edge structure only; reused by both RGCN layers)
    hipMemsetAsync(CNTI, 0, 2 * NN * sizeof(int), stream);
    cnt_i_k<<<(EE + 255) / 256, blk, 0, stream>>>(edst, ety, CNTI);
    part_k<<<SCAN_NB, blk, 0, stream>>>(CNTI, PART);
    scanp_k<<<1, 128, 0, stream>>>(PART);
    offs_k<<<SCAN_NB, blk, 0, stream>>>(CNTI, PART, OFFS);
    fill_k<<<(EE + 255) / 256, blk, 0, stream>>>(esrc, edst, ety, OFFS, ELIST);

    // ---- input embedding
    gemm_mfma<4, true, true, false, false, false, false, false><<<gx, blk, 0, stream>>>(
        tweet, WTt, bt, nullptr, B0, nullptr, nullptr, nullptr, nullptr, NN, 768, DDIM);
    embed_nc_k<<<(NN * 128 + 255) / 256, blk, 0, stream>>>(np_, cp, Wn, bnum, Wc, bc, B0);

    // ---- 6 layers
    for (int i = 0; i < NLAYER; ++i) {
        const size_t wo = (size_t)i * 36864;
        gemm_mfma<12, true, false, false, false, false, false, false><<<gx, blk, 0, stream>>>(
            B0, WTv + wo, bv + i * DDIM, nullptr, B1, nullptr, nullptr, nullptr, nullptr, NN, DDIM, DDIM);
        hipMemsetAsync(BNS, 0, 2 * DDIM * sizeof(float), stream);
        // x = ln1(x + v@Wo + bo), fused BN-stat accumulation
        gemm_mfma<12, true, false, true, true, false, false, true><<<gx, blk, 0, stream>>>(
            B1, WTo + wo, bo + i * DDIM, B0, B2, nullptr, BNS, ln1g + i * DDIM, ln1b + i * DDIM, NN, DDIM, DDIM);
        bn_fin_k<<<1, dim3(192), 0, stream>>>(BNS, bng + i * DDIM, bnb + i * DDIM);
        // f1 = lrelu(bn(x)@W1 + b1)   (BN applied on A-load)
        gemm_mfma<12, true, true, false, false, true, false, false><<<gx, blk, 0, stream>>>(
            B2, WT1 + wo, b1 + i * DDIM, nullptr, B1, BNS, nullptr, nullptr, nullptr, NN, DDIM, DDIM);
        // x = ln2(bn(x) + f1@W2 + b2) (BN applied on residual read)
        gemm_mfma<12, true, false, true, true, false, true, false><<<gx, blk, 0, stream>>>(
            B1, WT2 + wo, b2 + i * DDIM, B2, B0, BNS, nullptr, ln2g + i * DDIM, ln2b + i * DDIM, NN, DDIM, DDIM);
    }

    // ---- contrastive loss (before RGCN so AGG can reuse B2/B3)
    hipMemsetAsync(ROWEX, 0, 2 * TRAIN * sizeof(float), stream);
    fnorm_k<<<TRAIN / 4, blk, 0, stream>>>(B0, FNb);
    sim_mfma<<<dim3(TRAIN / 128, TRAIN / 128), blk, 0, stream>>>(FNb, labels, ROWEX, ROWMT);
    closs_k<<<1, blk, 0, stream>>>(ROWEX, ROWMT, out + 2 * (size_t)NN);

    // ---- RGCN pass 1:  h = x@Wroot + b + [m0|m1]@[W0;W1]    (B0 -> B0)
    gather_k<<<(NN + 3) / 4, blk, 0, stream>>>(B0, ELIST, OFFS, CNTI, AGG);
    gemm_mfma<12, true, false, false, false, false, false, false><<<gx, blk, 0, stream>>>(
        B0, WTroot, rgcnb, nullptr, B1, nullptr, nullptr, nullptr, nullptr, NN, DDIM, DDIM);
    gemm_mfma<12, false, false, true, false, false, false, false><<<gx, blk, 0, stream>>>(
        AGG, WTc, nullptr, B1, B0, nullptr, nullptr, nullptr, nullptr, NN, 384, DDIM);

    // ---- RGCN pass 2 (B0 -> B0)
    gather_k<<<(NN + 3) / 4, blk, 0, stream>>>(B0, ELIST, OFFS, CNTI, AGG);
    gemm_mfma<12, true, false, false, false, false, false, false><<<gx, blk, 0, stream>>>(
        B0, WTroot, rgcnb, nullptr, B1, nullptr, nullptr, nullptr, nullptr, NN, DDIM, DDIM);
    gemm_mfma<12, false, false, true, false, false, false, false><<<gx, blk, 0, stream>>>(
        AGG, WTc, nullptr, B1, B0, nullptr, nullptr, nullptr, nullptr, NN, 384, DDIM);

    // ---- MLP head
    gemm_mfma<12, true, true, false, false, false, false, false><<<gx, blk, 0, stream>>>(
        B0, WTm1, bm1, nullptr, B1, nullptr, nullptr, nullptr, nullptr, NN, DDIM, DDIM);
    gemm_mfma<12, true, true, false, false, false, false, false><<<gx, blk, 0, stream>>>(
        B1, WTm2, bm2, nullptr, B2, nullptr, nullptr, nullptr, nullptr, NN, DDIM, DDIM);
    logits_k<<<(NN + 3) / 4, blk, 0, stream>>>(B2, Wm3, bm3, out);
}